// Round 13
// baseline (330.185 us; speedup 1.0000x reference)
//
#include <hip/hip_runtime.h>
#include <stdint.h>

#define S_LEN 4096
#define DM 1024
#define NH 16

typedef __attribute__((ext_vector_type(8))) short short8;
typedef __attribute__((ext_vector_type(4))) float float4v;
typedef __attribute__((ext_vector_type(4))) unsigned short ushort4v;

typedef __attribute__((address_space(1))) const void* as1cvp;
typedef __attribute__((address_space(3))) void* as3vp;

#define MFMA16(a, b, c) __builtin_amdgcn_mfma_f32_16x16x32_bf16((a), (b), (c), 0, 0, 0)
#define GLOAD_LDS16(g, l) \
  __builtin_amdgcn_global_load_lds((as1cvp)(g), (as3vp)(l), 16, 0, 0)

__device__ __forceinline__ unsigned short f2bf(float f) {
  unsigned u = __float_as_uint(f);
  u += 0x7fffu + ((u >> 16) & 1u);
  return (unsigned short)(u >> 16);
}

__device__ __forceinline__ float exp2_hw(float x) {
  float r;
  asm("v_exp_f32 %0, %1" : "=v"(r) : "v"(x));
  return r;
}

// ---------------- cast fp32 -> bf16 into workspace ----------------
__global__ __launch_bounds__(256) void cast_all(
    const float* __restrict__ q, const float* __restrict__ k, const float* __restrict__ v,
    const float* __restrict__ wq, const float* __restrict__ wk, const float* __restrict__ wv,
    const float* __restrict__ wo, unsigned short* __restrict__ dst)
{
  const float* src; size_t off; int n;
  switch (blockIdx.y) {
    case 0: src = q;  off = 0u;        n = 4194304; break;
    case 1: src = k;  off = 4194304u;  n = 4194304; break;
    case 2: src = v;  off = 8388608u;  n = 4194304; break;
    case 3: src = wq; off = 12582912u; n = 1048576; break;
    case 4: src = wk; off = 13631488u; n = 1048576; break;
    case 5: src = wv; off = 14680064u; n = 1048576; break;
    default: src = wo; off = 15728640u; n = 1048576; break;
  }
  int nv = n >> 2;
  for (int i = blockIdx.x * blockDim.x + threadIdx.x; i < nv; i += gridDim.x * blockDim.x) {
    float4v val = ((const float4v*)src)[i];
    ushort4v o;
    o.x = f2bf(val.x); o.y = f2bf(val.y); o.z = f2bf(val.z); o.w = f2bf(val.w);
    ((ushort4v*)(dst + off))[i] = o;
  }
}

// ---------------- 128x128 bt-GEMM tile (m97 structure) ----------------
// MODE 0: bf16 row-major out; MODE 1: f32 row-major out; MODE 2: bf16 TRANSPOSED out [N][4096]
template<int MODE>
__device__ __forceinline__ void gemm128(
    const unsigned short* __restrict__ A, const unsigned short* __restrict__ Bw,
    unsigned short* Cb, float* Cf, const float* __restrict__ bias, float alpha,
    unsigned short* As, unsigned short* Bs)
{
  const int K = 1024, N = 1024;
  int bm = blockIdx.x, bn = blockIdx.y;
  int t = threadIdx.x, lane = t & 63, w = t >> 6;
  int l15 = lane & 15, l4 = lane >> 4;
  int wr = w >> 1, wc = w & 1;

  float4v acc[4][4] = {};

  for (int kt = 0; kt < K / 32; ++kt) {
#pragma unroll
    for (int i = 0; i < 2; ++i) {
      int ci = i * 256 + t;
      int r = ci >> 2, cb = ci & 3;
      GLOAD_LDS16(A + (size_t)(bm * 128 + r) * K + kt * 32 + cb * 8,
                  As + (size_t)(i * 256 + w * 64) * 8);
      GLOAD_LDS16(Bw + (size_t)(bn * 128 + r) * K + kt * 32 + cb * 8,
                  Bs + (size_t)(i * 256 + w * 64) * 8);
    }
    __syncthreads();
    short8 af[4], bfr[4];
#pragma unroll
    for (int mf = 0; mf < 4; ++mf)
      af[mf] = *(const short8*)&As[(wr * 64 + mf * 16 + l15) * 32 + l4 * 8];
#pragma unroll
    for (int nf = 0; nf < 4; ++nf)
      bfr[nf] = *(const short8*)&Bs[(wc * 64 + nf * 16 + l15) * 32 + l4 * 8];
#pragma unroll
    for (int mf = 0; mf < 4; ++mf)
#pragma unroll
      for (int nf = 0; nf < 4; ++nf)
        acc[mf][nf] = MFMA16(af[mf], bfr[nf], acc[mf][nf]);
    __syncthreads();
  }

#pragma unroll
  for (int mf = 0; mf < 4; ++mf)
#pragma unroll
    for (int nf = 0; nf < 4; ++nf) {
      int col = bn * 128 + wc * 64 + nf * 16 + l15;
      float bv = bias[col];
#pragma unroll
      for (int j = 0; j < 4; ++j) {
        int row = bm * 128 + wr * 64 + mf * 16 + l4 * 4 + j;
        float val = (acc[mf][nf][j] + bv) * alpha;
        if (MODE == 1)      Cf[(size_t)row * N + col] = val;
        else if (MODE == 2) Cb[(size_t)col * S_LEN + row] = f2bf(val);  // transposed
        else                Cb[(size_t)row * N + col] = f2bf(val);
      }
    }
}

__global__ __launch_bounds__(256) void proj_qkv(
    const unsigned short* xq, const unsigned short* xk, const unsigned short* xv,
    const unsigned short* wq, const unsigned short* wk, const unsigned short* wv,
    unsigned short* Qp, unsigned short* Kp, unsigned short* Vt,
    const float* bq, const float* bk, const float* bv)
{
  __shared__ unsigned short As[128 * 32], Bs[128 * 32];
  switch (blockIdx.z) {
    // Q scale = (1/sqrt(64)) * log2(e): softmax runs in exp2 domain
    case 0:  gemm128<0>(xq, wq, Qp, nullptr, bq, 0.1803368867f, As, Bs); break;
    case 1:  gemm128<0>(xk, wk, Kp, nullptr, bk, 1.0f,          As, Bs); break;
    default: gemm128<2>(xv, wv, Vt, nullptr, bv, 1.0f,          As, Bs); break; // V^T [1024][4096]
  }
}

__global__ __launch_bounds__(256) void proj_o(
    const unsigned short* ctx, const unsigned short* wo, float* out, const float* bo)
{
  __shared__ unsigned short As[128 * 32], Bs[128 * 32];
  gemm128<1>(ctx, wo, nullptr, out, bo, 1.0f, As, Bs);
}

// ---------------- fused flash attention ----------------
// 512 blocks (XCD-swizzled) x 512 threads (8 waves), wave = 16 q rows.
// r6-proven structure with three deltas:
//  (1) V fragments read DIRECT FROM GLOBAL (L1-resident: all 8 waves of a block
//      read identical V-frags) -> V leaves the DS pipe entirely; VMEM latency
//      hides under the softmax chain (loads issued before softmax).
//  (2) exp2-domain softmax (Q pre-scaled by 0.125*log2e), defer-max THR=11.5.
//  (3) l_run kept as per-lane partials (corr row-uniform => exact), reduced once.
// K staged in LDS (XOR-swizzled, dbuf); P via per-wave LDS round-trip (proven).
template<int BUF>
__device__ __forceinline__ void attn_tile(
    int kt,
    const unsigned short* kb0, const unsigned short* kb1,
    const unsigned short* const (&vrow)[4],
    unsigned short* pw, const unsigned short* pr,
    const unsigned short* kg, unsigned short* kls,
    const short8 (&qf)[2], float4v (&acc_o)[4], float& m_run, float& l_run,
    int l4)
{
  if (kt + 1 < 64)   // prefetch next K tile into the other buffer
    GLOAD_LDS16(kg + (size_t)(kt + 1) * (64 * DM), kls + (1 - BUF) * 4096);

  // ---- QK^T (swapped: A = K rows, B = Q rows) ----
  float4v sc[4];
#pragma unroll
  for (int nf = 0; nf < 4; ++nf) {
    short8 kf0 = *(const short8*)(kb0 + BUF * 4096 + nf * 1024);
    short8 kf1 = *(const short8*)(kb1 + BUF * 4096 + nf * 1024);
    float4v z = {0.f, 0.f, 0.f, 0.f};
    z = MFMA16(kf0, qf[0], z);
    sc[nf] = MFMA16(kf1, qf[1], z);
  }

  // ---- V B-fragments from GLOBAL (issued early; consumed after softmax) ----
  short8 vf[4][2];
  const int ktoff = kt * 64;
#pragma unroll
  for (int nfd = 0; nfd < 4; ++nfd)
#pragma unroll
    for (int kc = 0; kc < 2; ++kc)
      vf[nfd][kc] = *(const short8*)(vrow[nfd] + ktoff + kc * 32);

  // ---- row max (q = l15), exp2 domain ----
  float mx = fmaxf(fmaxf(fmaxf(sc[0][0], sc[0][1]), sc[0][2]), sc[0][3]);
#pragma unroll
  for (int nf = 1; nf < 4; ++nf)
    mx = fmaxf(fmaxf(fmaxf(fmaxf(mx, sc[nf][0]), sc[nf][1]), sc[nf][2]), sc[nf][3]);
  mx = fmaxf(mx, __shfl_xor(mx, 16));
  mx = fmaxf(mx, __shfl_xor(mx, 32));

  if (!__all(mx <= m_run + 11.5f)) {   // defer-max (11.5 = 8 nats in log2 units)
    float mnew = fmaxf(m_run, mx);
    float corr = exp2_hw(m_run - mnew);
    m_run = mnew;
    l_run *= corr;                     // valid on per-lane partials (row-uniform corr)
#pragma unroll
    for (int j = 0; j < 4; ++j) {
      float cj = __shfl(corr, l4 * 4 + j);
#pragma unroll
      for (int nf2 = 0; nf2 < 4; ++nf2) acc_o[nf2][j] *= cj;
    }
  }

  // ---- exp2 + packed bf16 conversion + P write ----
  float ps = 0.f;
#pragma unroll
  for (int nf = 0; nf < 4; ++nf) {
    float p0 = exp2_hw(sc[nf][0] - m_run);
    float p1 = exp2_hw(sc[nf][1] - m_run);
    float p2 = exp2_hw(sc[nf][2] - m_run);
    float p3 = exp2_hw(sc[nf][3] - m_run);
    ps += (p0 + p1) + (p2 + p3);
    unsigned lo, hi;
    asm("v_cvt_pk_bf16_f32 %0, %1, %2" : "=v"(lo) : "v"(p0), "v"(p1));
    asm("v_cvt_pk_bf16_f32 %0, %1, %2" : "=v"(hi) : "v"(p2), "v"(p3));
    uint2 u; u.x = lo; u.y = hi;
    *(uint2*)(pw + nf * 16) = u;   // ds_write_b64
  }
  l_run += ps;   // per-lane partial (16 k-cols of row l15); reduced once at the end

  // ---- P A-fragments (same-wave RAW through LDS) ----
  short8 pf[2];
#pragma unroll
  for (int kc = 0; kc < 2; ++kc)
    pf[kc] = *(const short8*)(pr + kc * 32);

  // ---- PV (V fragments already in registers) ----
#pragma unroll
  for (int nfd = 0; nfd < 4; ++nfd) {
    acc_o[nfd] = MFMA16(pf[0], vf[nfd][0], acc_o[nfd]);
    acc_o[nfd] = MFMA16(pf[1], vf[nfd][1], acc_o[nfd]);
  }
  __syncthreads();   // drains K prefetch (vmcnt) + all waves done with buf[BUF]
}

__global__ __launch_bounds__(512) void attn_fused(
    const unsigned short* __restrict__ Qp, const unsigned short* __restrict__ Kp,
    const unsigned short* __restrict__ Vt, unsigned short* __restrict__ ctx)
{
  __shared__ unsigned short Ks[2][64 * 64];
  __shared__ unsigned short Ps[8][16 * 72];

  // bijective XCD swizzle: 512 blocks, 64 consecutive wg per XCD
  int bid = blockIdx.x;
  int wg = (bid & 7) * 64 + (bid >> 3);
  int h = wg >> 5, qt = wg & 31;

  int t = threadIdx.x, lane = t & 63, w = t >> 6;
  int l15 = lane & 15, l4 = lane >> 4;

  // Q fragments (pre-scaled by 0.125*log2e in projection)
  short8 qf[2];
  int qrow0 = qt * 128 + w * 16;
#pragma unroll
  for (int ks = 0; ks < 2; ++ks)
    qf[ks] = *(const short8*)&Qp[(size_t)(qrow0 + l15) * DM + h * 64 + ks * 32 + l4 * 8];

  float4v acc_o[4] = {};
  float m_run = -INFINITY, l_run = 0.f;

  // ---- precomputed per-lane LDS addresses (K swizzled; P per-wave) ----
  const int swz = l15 & 7;
  const unsigned short* kb0 = &Ks[0][l15 * 64 + ((l4) ^ swz) * 8];
  const unsigned short* kb1 = &Ks[0][l15 * 64 + ((4 + l4) ^ swz) * 8];
  unsigned short* pw = &Ps[w][l15 * 72 + l4 * 4];
  const unsigned short* pr = &Ps[w][l15 * 72 + l4 * 8];

  // ---- V global fragment row bases (b128 per (nfd,kc); identical across waves) ----
  const unsigned short* vrow[4];
#pragma unroll
  for (int nfd = 0; nfd < 4; ++nfd)
    vrow[nfd] = Vt + (size_t)(h * 64 + nfd * 16 + l15) * S_LEN + l4 * 8;

  // ---- K staging addresses (512 threads: 1 K-load each per tile) ----
  int sr = t >> 3, sp = t & 7;
  int slb = sp ^ (sr & 7);
  const unsigned short* kg = Kp + (size_t)sr * DM + h * 64 + slb * 8;
  unsigned short* kls = &Ks[0][t * 8];

  GLOAD_LDS16(kg, kls);
  __syncthreads();

  for (int kt = 0; kt < 64; kt += 2) {
    attn_tile<0>(kt,     kb0, kb1, vrow, pw, pr, kg, kls, qf, acc_o, m_run, l_run, l4);
    attn_tile<1>(kt + 1, kb0, kb1, vrow, pw, pr, kg, kls, qf, acc_o, m_run, l_run, l4);
  }

  // ---- final l reduction + normalize + write ctx (bf16) ----
  float lr = l_run;
  lr += __shfl_xor(lr, 16);
  lr += __shfl_xor(lr, 32);
#pragma unroll
  for (int j = 0; j < 4; ++j) {
    float lj = __shfl(lr, l4 * 4 + j);   // lane l4*4+j has l15 == l4*4+j (full row sum)
    float inv = 1.0f / lj;
#pragma unroll
    for (int nfd = 0; nfd < 4; ++nfd) {
      int row = qrow0 + l4 * 4 + j;
      int col = h * 64 + nfd * 16 + l15;
      ctx[(size_t)row * DM + col] = f2bf(acc_o[nfd][j] * inv);
    }
  }
}

// ---------------- launcher ----------------
extern "C" void kernel_launch(void* const* d_in, const int* in_sizes, int n_in,
                              void* d_out, int out_size, void* d_ws, size_t ws_size,
                              hipStream_t stream) {
  const float* q  = (const float*)d_in[0];
  const float* k  = (const float*)d_in[1];
  const float* v  = (const float*)d_in[2];
  const float* wq = (const float*)d_in[3];
  const float* bq = (const float*)d_in[4];
  const float* wk = (const float*)d_in[5];
  const float* bk = (const float*)d_in[6];
  const float* wv = (const float*)d_in[7];
  const float* bv = (const float*)d_in[8];
  const float* wo = (const float*)d_in[9];
  const float* bo = (const float*)d_in[10];

  unsigned short* ws  = (unsigned short*)d_ws;
  unsigned short* qb  = ws;                 // 4M elems (reused as ctx later)
  unsigned short* kb  = ws + 4194304u;
  unsigned short* vb  = ws + 8388608u;
  unsigned short* wqb = ws + 12582912u;
  unsigned short* wkb = ws + 13631488u;
  unsigned short* wvb = ws + 14680064u;
  unsigned short* wob = ws + 15728640u;
  unsigned short* Qp  = ws + 16777216u;
  unsigned short* Kp  = ws + 20971520u;
  unsigned short* Vt  = ws + 25165824u;     // V^T [1024][4096]
  unsigned short* ctx = qb;                 // safe reuse: qb consumed by proj_qkv before attn
  float* out = (float*)d_out;

  cast_all<<<dim3(1024, 7), 256, 0, stream>>>(q, k, v, wq, wk, wv, wo, ws);
  proj_qkv<<<dim3(32, 8, 3), 256, 0, stream>>>(qb, kb, vb, wqb, wkb, wvb, Qp, Kp, Vt, bq, bk, bv);
  attn_fused<<<dim3(512), 512, 0, stream>>>(Qp, Kp, Vt, ctx);
  proj_o<<<dim3(32, 8), 256, 0, stream>>>(ctx, wob, out, bo);
}

// Round 14
// 184.750 us; speedup vs baseline: 1.7872x; 1.7872x over previous
//
#include <hip/hip_runtime.h>
#include <stdint.h>

#define S_LEN 4096
#define DM 1024
#define NH 16

typedef __attribute__((ext_vector_type(8))) short short8;
typedef __attribute__((ext_vector_type(4))) float float4v;
typedef __attribute__((ext_vector_type(4))) unsigned short ushort4v;

typedef __attribute__((address_space(1))) const void* as1cvp;
typedef __attribute__((address_space(3))) void* as3vp;

#define MFMA16(a, b, c) __builtin_amdgcn_mfma_f32_16x16x32_bf16((a), (b), (c), 0, 0, 0)
#define GLOAD_LDS16(g, l) \
  __builtin_amdgcn_global_load_lds((as1cvp)(g), (as3vp)(l), 16, 0, 0)

__device__ __forceinline__ unsigned short f2bf(float f) {
  unsigned u = __float_as_uint(f);
  u += 0x7fffu + ((u >> 16) & 1u);
  return (unsigned short)(u >> 16);
}

__device__ __forceinline__ float exp2_hw(float x) {
  float r;
  asm("v_exp_f32 %0, %1" : "=v"(r) : "v"(x));
  return r;
}

// ---------------- cast fp32 -> bf16 into workspace ----------------
__global__ __launch_bounds__(256) void cast_all(
    const float* __restrict__ q, const float* __restrict__ k, const float* __restrict__ v,
    const float* __restrict__ wq, const float* __restrict__ wk, const float* __restrict__ wv,
    const float* __restrict__ wo, unsigned short* __restrict__ dst)
{
  const float* src; size_t off; int n;
  switch (blockIdx.y) {
    case 0: src = q;  off = 0u;        n = 4194304; break;
    case 1: src = k;  off = 4194304u;  n = 4194304; break;
    case 2: src = v;  off = 8388608u;  n = 4194304; break;
    case 3: src = wq; off = 12582912u; n = 1048576; break;
    case 4: src = wk; off = 13631488u; n = 1048576; break;
    case 5: src = wv; off = 14680064u; n = 1048576; break;
    default: src = wo; off = 15728640u; n = 1048576; break;
  }
  int nv = n >> 2;
  for (int i = blockIdx.x * blockDim.x + threadIdx.x; i < nv; i += gridDim.x * blockDim.x) {
    float4v val = ((const float4v*)src)[i];
    ushort4v o;
    o.x = f2bf(val.x); o.y = f2bf(val.y); o.z = f2bf(val.z); o.w = f2bf(val.w);
    ((ushort4v*)(dst + off))[i] = o;
  }
}

// ---------------- 128x128 bt-GEMM tile (m97 structure) ----------------
// MODE 0: bf16 row-major out; MODE 1: f32 row-major out; MODE 2: bf16 TRANSPOSED out [N][4096]
template<int MODE>
__device__ __forceinline__ void gemm128(
    const unsigned short* __restrict__ A, const unsigned short* __restrict__ Bw,
    unsigned short* Cb, float* Cf, const float* __restrict__ bias, float alpha,
    unsigned short* As, unsigned short* Bs)
{
  const int K = 1024, N = 1024;
  int bm = blockIdx.x, bn = blockIdx.y;
  int t = threadIdx.x, lane = t & 63, w = t >> 6;
  int l15 = lane & 15, l4 = lane >> 4;
  int wr = w >> 1, wc = w & 1;

  float4v acc[4][4] = {};

  for (int kt = 0; kt < K / 32; ++kt) {
#pragma unroll
    for (int i = 0; i < 2; ++i) {
      int ci = i * 256 + t;
      int r = ci >> 2, cb = ci & 3;
      GLOAD_LDS16(A + (size_t)(bm * 128 + r) * K + kt * 32 + cb * 8,
                  As + (size_t)(i * 256 + w * 64) * 8);
      GLOAD_LDS16(Bw + (size_t)(bn * 128 + r) * K + kt * 32 + cb * 8,
                  Bs + (size_t)(i * 256 + w * 64) * 8);
    }
    __syncthreads();
    short8 af[4], bfr[4];
#pragma unroll
    for (int mf = 0; mf < 4; ++mf)
      af[mf] = *(const short8*)&As[(wr * 64 + mf * 16 + l15) * 32 + l4 * 8];
#pragma unroll
    for (int nf = 0; nf < 4; ++nf)
      bfr[nf] = *(const short8*)&Bs[(wc * 64 + nf * 16 + l15) * 32 + l4 * 8];
#pragma unroll
    for (int mf = 0; mf < 4; ++mf)
#pragma unroll
      for (int nf = 0; nf < 4; ++nf)
        acc[mf][nf] = MFMA16(af[mf], bfr[nf], acc[mf][nf]);
    __syncthreads();
  }

#pragma unroll
  for (int mf = 0; mf < 4; ++mf)
#pragma unroll
    for (int nf = 0; nf < 4; ++nf) {
      int col = bn * 128 + wc * 64 + nf * 16 + l15;
      float bv = bias[col];
#pragma unroll
      for (int j = 0; j < 4; ++j) {
        int row = bm * 128 + wr * 64 + mf * 16 + l4 * 4 + j;
        float val = (acc[mf][nf][j] + bv) * alpha;
        if (MODE == 1)      Cf[(size_t)row * N + col] = val;
        else if (MODE == 2) Cb[(size_t)col * S_LEN + row] = f2bf(val);  // transposed
        else                Cb[(size_t)row * N + col] = f2bf(val);
      }
    }
}

__global__ __launch_bounds__(256) void proj_qkv(
    const unsigned short* xq, const unsigned short* xk, const unsigned short* xv,
    const unsigned short* wq, const unsigned short* wk, const unsigned short* wv,
    unsigned short* Qp, unsigned short* Kp, unsigned short* Vt,
    const float* bq, const float* bk, const float* bv)
{
  __shared__ unsigned short As[128 * 32], Bs[128 * 32];
  switch (blockIdx.z) {
    // Q scale = (1/sqrt(64)) * log2(e): softmax runs in exp2 domain
    case 0:  gemm128<0>(xq, wq, Qp, nullptr, bq, 0.1803368867f, As, Bs); break;
    case 1:  gemm128<0>(xk, wk, Kp, nullptr, bk, 1.0f,          As, Bs); break;
    default: gemm128<2>(xv, wv, Vt, nullptr, bv, 1.0f,          As, Bs); break; // V^T [1024][4096]
  }
}

__global__ __launch_bounds__(256) void proj_o(
    const unsigned short* ctx, const unsigned short* wo, float* out, const float* bo)
{
  __shared__ unsigned short As[128 * 32], Bs[128 * 32];
  gemm128<1>(ctx, wo, nullptr, out, bo, 1.0f, As, Bs);
}

// ---------------- fused flash attention ----------------
// EXACT round-6 structure (best measured: 117.7 us) + two HW-proven deltas:
//  (a) exp2-domain softmax (Q pre-scaled by 0.125*log2e; defer-max THR=11.5)
//  (b) l_run as per-lane partials (corr row-uniform => exact), reduced once at end
// 512 blocks (XCD-swizzled) x 512 threads (8 waves), wave = 16 q rows.
// KV tile 64, static unroll-2 double buffer, precomputed DS addresses,
// swapped QK^T -> in-register row ownership; P via cvt_pk + per-wave LDS.
template<int BUF>
__device__ __forceinline__ void attn_tile(
    int kt,
    const unsigned short* kb0, const unsigned short* kb1,
    const unsigned short* vb0, const unsigned short* vb1,
    unsigned short* pw, const unsigned short* pr,
    const unsigned short* kg, const unsigned short* vg,
    unsigned short* kls, unsigned short* vls,
    const short8 (&qf)[2], float4v (&acc_o)[4], float& m_run, float& l_run,
    int l4)
{
  if (kt + 1 < 64) {   // prefetch next tile into the other buffer
    GLOAD_LDS16(kg + (size_t)(kt + 1) * (64 * DM), kls + (1 - BUF) * 4096);
    GLOAD_LDS16(vg + (kt + 1) * 64, vls + (1 - BUF) * 4096);
  }

  // ---- QK^T (swapped: A = K rows, B = Q rows) ----
  float4v sc[4];
#pragma unroll
  for (int nf = 0; nf < 4; ++nf) {
    short8 kf0 = *(const short8*)(kb0 + BUF * 4096 + nf * 1024);
    short8 kf1 = *(const short8*)(kb1 + BUF * 4096 + nf * 1024);
    float4v z = {0.f, 0.f, 0.f, 0.f};
    z = MFMA16(kf0, qf[0], z);
    sc[nf] = MFMA16(kf1, qf[1], z);
  }

  // ---- row max (q = l15), exp2 domain ----
  float mx = fmaxf(fmaxf(fmaxf(sc[0][0], sc[0][1]), sc[0][2]), sc[0][3]);
#pragma unroll
  for (int nf = 1; nf < 4; ++nf)
    mx = fmaxf(fmaxf(fmaxf(fmaxf(mx, sc[nf][0]), sc[nf][1]), sc[nf][2]), sc[nf][3]);
  mx = fmaxf(mx, __shfl_xor(mx, 16));
  mx = fmaxf(mx, __shfl_xor(mx, 32));

  if (!__all(mx <= m_run + 11.5f)) {   // defer-max (11.5 = 8 nats in log2 units)
    float mnew = fmaxf(m_run, mx);
    float corr = exp2_hw(m_run - mnew);
    m_run = mnew;
    l_run *= corr;                     // valid on per-lane partials (row-uniform corr)
#pragma unroll
    for (int j = 0; j < 4; ++j) {
      float cj = __shfl(corr, l4 * 4 + j);
#pragma unroll
      for (int nf2 = 0; nf2 < 4; ++nf2) acc_o[nf2][j] *= cj;
    }
  }

  // ---- exp2 + packed bf16 conversion + P write ----
  float ps = 0.f;
#pragma unroll
  for (int nf = 0; nf < 4; ++nf) {
    float p0 = exp2_hw(sc[nf][0] - m_run);
    float p1 = exp2_hw(sc[nf][1] - m_run);
    float p2 = exp2_hw(sc[nf][2] - m_run);
    float p3 = exp2_hw(sc[nf][3] - m_run);
    ps += (p0 + p1) + (p2 + p3);
    unsigned lo, hi;
    asm("v_cvt_pk_bf16_f32 %0, %1, %2" : "=v"(lo) : "v"(p0), "v"(p1));
    asm("v_cvt_pk_bf16_f32 %0, %1, %2" : "=v"(hi) : "v"(p2), "v"(p3));
    uint2 u; u.x = lo; u.y = hi;
    *(uint2*)(pw + nf * 16) = u;   // ds_write_b64
  }
  l_run += ps;   // per-lane partial (16 k-cols of row l15); reduced once at the end

  // ---- P A-fragments (same-wave RAW through LDS) ----
  short8 pf[2];
#pragma unroll
  for (int kc = 0; kc < 2; ++kc)
    pf[kc] = *(const short8*)(pr + kc * 32);

  // ---- PV: V^T B-fragments (swizzled LDS read) ----
#pragma unroll
  for (int nfd = 0; nfd < 4; ++nfd) {
    short8 vf0 = *(const short8*)(vb0 + BUF * 4096 + nfd * 1024);
    short8 vf1 = *(const short8*)(vb1 + BUF * 4096 + nfd * 1024);
    acc_o[nfd] = MFMA16(pf[0], vf0, acc_o[nfd]);
    acc_o[nfd] = MFMA16(pf[1], vf1, acc_o[nfd]);
  }
  __syncthreads();   // drains prefetch (vmcnt) + all waves done with buf[BUF]
}

__global__ __launch_bounds__(512) void attn_fused(
    const unsigned short* __restrict__ Qp, const unsigned short* __restrict__ Kp,
    const unsigned short* __restrict__ Vt, unsigned short* __restrict__ ctx)
{
  __shared__ unsigned short Ks[2][64 * 64];
  __shared__ unsigned short Vts[2][64 * 64];
  __shared__ unsigned short Ps[8][16 * 72];

  // bijective XCD swizzle: 512 blocks, 64 consecutive wg per XCD
  int bid = blockIdx.x;
  int wg = (bid & 7) * 64 + (bid >> 3);
  int h = wg >> 5, qt = wg & 31;

  int t = threadIdx.x, lane = t & 63, w = t >> 6;
  int l15 = lane & 15, l4 = lane >> 4;

  // Q fragments (pre-scaled by 0.125*log2e in projection)
  short8 qf[2];
  int qrow0 = qt * 128 + w * 16;
#pragma unroll
  for (int ks = 0; ks < 2; ++ks)
    qf[ks] = *(const short8*)&Qp[(size_t)(qrow0 + l15) * DM + h * 64 + ks * 32 + l4 * 8];

  float4v acc_o[4] = {};
  float m_run = -INFINITY, l_run = 0.f;

  // ---- precomputed per-lane LDS addresses ----
  const int swz = l15 & 7;
  const unsigned short* kb0 = &Ks[0][l15 * 64 + ((l4) ^ swz) * 8];
  const unsigned short* kb1 = &Ks[0][l15 * 64 + ((4 + l4) ^ swz) * 8];
  const unsigned short* vb0 = &Vts[0][l15 * 64 + ((l4) ^ swz) * 8];
  const unsigned short* vb1 = &Vts[0][l15 * 64 + ((4 + l4) ^ swz) * 8];
  unsigned short* pw = &Ps[w][l15 * 72 + l4 * 4];
  const unsigned short* pr = &Ps[w][l15 * 72 + l4 * 8];

  // ---- staging addresses (512 threads: 1 K-load + 1 V-load each per tile) ----
  int sr = t >> 3, sp = t & 7;
  int slb = sp ^ (sr & 7);
  const unsigned short* kg = Kp + (size_t)sr * DM + h * 64 + slb * 8;
  const unsigned short* vg = Vt + (size_t)(h * 64 + sr) * S_LEN + slb * 8;
  unsigned short* kls = &Ks[0][t * 8];
  unsigned short* vls = &Vts[0][t * 8];

  GLOAD_LDS16(kg, kls);
  GLOAD_LDS16(vg, vls);
  __syncthreads();

  for (int kt = 0; kt < 64; kt += 2) {
    attn_tile<0>(kt,     kb0, kb1, vb0, vb1, pw, pr, kg, vg, kls, vls, qf, acc_o, m_run, l_run, l4);
    attn_tile<1>(kt + 1, kb0, kb1, vb0, vb1, pw, pr, kg, vg, kls, vls, qf, acc_o, m_run, l_run, l4);
  }

  // ---- final l reduction + normalize + write ctx (bf16) ----
  float lr = l_run;
  lr += __shfl_xor(lr, 16);
  lr += __shfl_xor(lr, 32);
#pragma unroll
  for (int j = 0; j < 4; ++j) {
    float lj = __shfl(lr, l4 * 4 + j);   // lane l4*4+j has l15 == l4*4+j (full row sum)
    float inv = 1.0f / lj;
#pragma unroll
    for (int nfd = 0; nfd < 4; ++nfd) {
      int row = qrow0 + l4 * 4 + j;
      int col = h * 64 + nfd * 16 + l15;
      ctx[(size_t)row * DM + col] = f2bf(acc_o[nfd][j] * inv);
    }
  }
}

// ---------------- launcher ----------------
extern "C" void kernel_launch(void* const* d_in, const int* in_sizes, int n_in,
                              void* d_out, int out_size, void* d_ws, size_t ws_size,
                              hipStream_t stream) {
  const float* q  = (const float*)d_in[0];
  const float* k  = (const float*)d_in[1];
  const float* v  = (const float*)d_in[2];
  const float* wq = (const float*)d_in[3];
  const float* bq = (const float*)d_in[4];
  const float* wk = (const float*)d_in[5];
  const float* bk = (const float*)d_in[6];
  const float* wv = (const float*)d_in[7];
  const float* bv = (const float*)d_in[8];
  const float* wo = (const float*)d_in[9];
  const float* bo = (const float*)d_in[10];

  unsigned short* ws  = (unsigned short*)d_ws;
  unsigned short* qb  = ws;                 // 4M elems (reused as ctx later)
  unsigned short* kb  = ws + 4194304u;
  unsigned short* vb  = ws + 8388608u;
  unsigned short* wqb = ws + 12582912u;
  unsigned short* wkb = ws + 13631488u;
  unsigned short* wvb = ws + 14680064u;
  unsigned short* wob = ws + 15728640u;
  unsigned short* Qp  = ws + 16777216u;
  unsigned short* Kp  = ws + 20971520u;
  unsigned short* Vt  = ws + 25165824u;     // V^T [1024][4096]
  unsigned short* ctx = qb;                 // safe reuse: qb consumed by proj_qkv before attn
  float* out = (float*)d_out;

  cast_all<<<dim3(1024, 7), 256, 0, stream>>>(q, k, v, wq, wk, wv, wo, ws);
  proj_qkv<<<dim3(32, 8, 3), 256, 0, stream>>>(qb, kb, vb, wqb, wkb, wvb, Qp, Kp, Vt, bq, bk, bv);
  attn_fused<<<dim3(512), 512, 0, stream>>>(Qp, Kp, Vt, ctx);
  proj_o<<<dim3(32, 8), 256, 0, stream>>>(ctx, wob, out, bo);
}

// Round 15
// 183.649 us; speedup vs baseline: 1.7979x; 1.0060x over previous
//
#include <hip/hip_runtime.h>
#include <stdint.h>

#define S_LEN 4096
#define DM 1024
#define NH 16

typedef __attribute__((ext_vector_type(8))) short short8;
typedef __attribute__((ext_vector_type(4))) float float4v;
typedef __attribute__((ext_vector_type(4))) unsigned short ushort4v;

typedef __attribute__((address_space(1))) const void* as1cvp;
typedef __attribute__((address_space(3))) void* as3vp;

#define MFMA16(a, b, c) __builtin_amdgcn_mfma_f32_16x16x32_bf16((a), (b), (c), 0, 0, 0)
#define GLOAD_LDS16(g, l) \
  __builtin_amdgcn_global_load_lds((as1cvp)(g), (as3vp)(l), 16, 0, 0)

__device__ __forceinline__ unsigned short f2bf(float f) {
  unsigned u = __float_as_uint(f);
  u += 0x7fffu + ((u >> 16) & 1u);
  return (unsigned short)(u >> 16);
}

__device__ __forceinline__ float exp2_hw(float x) {
  float r;
  asm("v_exp_f32 %0, %1" : "=v"(r) : "v"(x));
  return r;
}

// ---------------- cast fp32 -> bf16 into workspace ----------------
__global__ __launch_bounds__(256) void cast_all(
    const float* __restrict__ q, const float* __restrict__ k, const float* __restrict__ v,
    const float* __restrict__ wq, const float* __restrict__ wk, const float* __restrict__ wv,
    const float* __restrict__ wo, unsigned short* __restrict__ dst)
{
  const float* src; size_t off; int n;
  switch (blockIdx.y) {
    case 0: src = q;  off = 0u;        n = 4194304; break;
    case 1: src = k;  off = 4194304u;  n = 4194304; break;
    case 2: src = v;  off = 8388608u;  n = 4194304; break;
    case 3: src = wq; off = 12582912u; n = 1048576; break;
    case 4: src = wk; off = 13631488u; n = 1048576; break;
    case 5: src = wv; off = 14680064u; n = 1048576; break;
    default: src = wo; off = 15728640u; n = 1048576; break;
  }
  int nv = n >> 2;
  for (int i = blockIdx.x * blockDim.x + threadIdx.x; i < nv; i += gridDim.x * blockDim.x) {
    float4v val = ((const float4v*)src)[i];
    ushort4v o;
    o.x = f2bf(val.x); o.y = f2bf(val.y); o.z = f2bf(val.z); o.w = f2bf(val.w);
    ((ushort4v*)(dst + off))[i] = o;
  }
}

// ---------------- 128x128 bt-GEMM tile (m97 structure) ----------------
// MODE 0: bf16 row-major out; MODE 1: f32 row-major out;
// MODE 2: bf16 TRANSPOSED out [N][4096] via LDS-transpose coalesced epilogue.
template<int MODE>
__device__ __forceinline__ void gemm128(
    const unsigned short* __restrict__ A, const unsigned short* __restrict__ Bw,
    unsigned short* Cb, float* Cf, const float* __restrict__ bias, float alpha,
    unsigned short* As, unsigned short* Bs, unsigned short* T)
{
  const int K = 1024, N = 1024;
  int bm = blockIdx.x, bn = blockIdx.y;
  int t = threadIdx.x, lane = t & 63, w = t >> 6;
  int l15 = lane & 15, l4 = lane >> 4;
  int wr = w >> 1, wc = w & 1;

  float4v acc[4][4] = {};

  for (int kt = 0; kt < K / 32; ++kt) {
#pragma unroll
    for (int i = 0; i < 2; ++i) {
      int ci = i * 256 + t;
      int r = ci >> 2, cb = ci & 3;
      GLOAD_LDS16(A + (size_t)(bm * 128 + r) * K + kt * 32 + cb * 8,
                  As + (size_t)(i * 256 + w * 64) * 8);
      GLOAD_LDS16(Bw + (size_t)(bn * 128 + r) * K + kt * 32 + cb * 8,
                  Bs + (size_t)(i * 256 + w * 64) * 8);
    }
    __syncthreads();
    short8 af[4], bfr[4];
#pragma unroll
    for (int mf = 0; mf < 4; ++mf)
      af[mf] = *(const short8*)&As[(wr * 64 + mf * 16 + l15) * 32 + l4 * 8];
#pragma unroll
    for (int nf = 0; nf < 4; ++nf)
      bfr[nf] = *(const short8*)&Bs[(wc * 64 + nf * 16 + l15) * 32 + l4 * 8];
#pragma unroll
    for (int mf = 0; mf < 4; ++mf)
#pragma unroll
      for (int nf = 0; nf < 4; ++nf)
        acc[mf][nf] = MFMA16(af[mf], bfr[nf], acc[mf][nf]);
    __syncthreads();
  }

  if (MODE == 2) {
    // ---- LDS-transpose epilogue: T[64][136] bf16, two wc-halves ----
#pragma unroll
    for (int hc = 0; hc < 2; ++hc) {
      if (wc == hc) {
#pragma unroll
        for (int mf = 0; mf < 4; ++mf)
#pragma unroll
          for (int nf = 0; nf < 4; ++nf) {
            int c = nf * 16 + l15;                       // n-local within half
            float bv = bias[bn * 128 + hc * 64 + c];
            ushort4v pk;
#pragma unroll
            for (int j = 0; j < 4; ++j) pk[j] = f2bf((acc[mf][nf][j] + bv) * alpha);
            *(ushort4v*)&T[c * 136 + wr * 64 + mf * 16 + l4 * 4] = pk;  // ds_write_b64
          }
      }
      __syncthreads();
      // coalesced copy: c = t>>2 (0..63), rseg = (t&3)*32
      {
        int c = t >> 2, rseg = (t & 3) * 32;
        size_t gbase = (size_t)(bn * 128 + hc * 64 + c) * S_LEN + bm * 128 + rseg;
#pragma unroll
        for (int s = 0; s < 4; ++s) {
          short8 vv = *(const short8*)&T[c * 136 + rseg + s * 8];
          *(short8*)&Cb[gbase + s * 8] = vv;
        }
      }
      __syncthreads();
    }
    return;
  }

#pragma unroll
  for (int mf = 0; mf < 4; ++mf)
#pragma unroll
    for (int nf = 0; nf < 4; ++nf) {
      int col = bn * 128 + wc * 64 + nf * 16 + l15;
      float bv = bias[col];
#pragma unroll
      for (int j = 0; j < 4; ++j) {
        int row = bm * 128 + wr * 64 + mf * 16 + l4 * 4 + j;
        float val = (acc[mf][nf][j] + bv) * alpha;
        if (MODE == 1) Cf[(size_t)row * N + col] = val;
        else           Cb[(size_t)row * N + col] = f2bf(val);
      }
    }
}

__global__ __launch_bounds__(256) void proj_qkv(
    const unsigned short* xq, const unsigned short* xk, const unsigned short* xv,
    const unsigned short* wq, const unsigned short* wk, const unsigned short* wv,
    unsigned short* Qp, unsigned short* Kp, unsigned short* Vt,
    const float* bq, const float* bk, const float* bv)
{
  __shared__ unsigned short As[128 * 32], Bs[128 * 32];
  __shared__ unsigned short T[64 * 136];   // MODE-2 transpose staging
  switch (blockIdx.z) {
    // Q scale = (1/sqrt(64)) * log2(e): softmax runs in exp2 domain
    case 0:  gemm128<0>(xq, wq, Qp, nullptr, bq, 0.1803368867f, As, Bs, T); break;
    case 1:  gemm128<0>(xk, wk, Kp, nullptr, bk, 1.0f,          As, Bs, T); break;
    default: gemm128<2>(xv, wv, Vt, nullptr, bv, 1.0f,          As, Bs, T); break; // V^T [1024][4096]
  }
}

__global__ __launch_bounds__(256) void proj_o(
    const unsigned short* ctx, const unsigned short* wo, float* out, const float* bo)
{
  __shared__ unsigned short As[128 * 32], Bs[128 * 32];
  gemm128<1>(ctx, wo, nullptr, out, bo, 1.0f, As, Bs, nullptr);
}

// ---------------- fused flash attention ----------------
// Round-14 proven structure (109.3 us) + T5 s_setprio around MFMA clusters.
// 512 blocks (XCD-swizzled) x 512 threads (8 waves), wave = 16 q rows.
// exp2-domain softmax, defer-max THR=11.5, per-lane partial l_run.
template<int BUF>
__device__ __forceinline__ void attn_tile(
    int kt,
    const unsigned short* kb0, const unsigned short* kb1,
    const unsigned short* vb0, const unsigned short* vb1,
    unsigned short* pw, const unsigned short* pr,
    const unsigned short* kg, const unsigned short* vg,
    unsigned short* kls, unsigned short* vls,
    const short8 (&qf)[2], float4v (&acc_o)[4], float& m_run, float& l_run,
    int l4)
{
  if (kt + 1 < 64) {   // prefetch next tile into the other buffer
    GLOAD_LDS16(kg + (size_t)(kt + 1) * (64 * DM), kls + (1 - BUF) * 4096);
    GLOAD_LDS16(vg + (kt + 1) * 64, vls + (1 - BUF) * 4096);
  }

  // ---- QK^T (swapped: A = K rows, B = Q rows) ----
  float4v sc[4];
  __builtin_amdgcn_s_setprio(1);
#pragma unroll
  for (int nf = 0; nf < 4; ++nf) {
    short8 kf0 = *(const short8*)(kb0 + BUF * 4096 + nf * 1024);
    short8 kf1 = *(const short8*)(kb1 + BUF * 4096 + nf * 1024);
    float4v z = {0.f, 0.f, 0.f, 0.f};
    z = MFMA16(kf0, qf[0], z);
    sc[nf] = MFMA16(kf1, qf[1], z);
  }
  __builtin_amdgcn_s_setprio(0);

  // ---- row max (q = l15), exp2 domain ----
  float mx = fmaxf(fmaxf(fmaxf(sc[0][0], sc[0][1]), sc[0][2]), sc[0][3]);
#pragma unroll
  for (int nf = 1; nf < 4; ++nf)
    mx = fmaxf(fmaxf(fmaxf(fmaxf(mx, sc[nf][0]), sc[nf][1]), sc[nf][2]), sc[nf][3]);
  mx = fmaxf(mx, __shfl_xor(mx, 16));
  mx = fmaxf(mx, __shfl_xor(mx, 32));

  if (!__all(mx <= m_run + 11.5f)) {   // defer-max (11.5 = 8 nats in log2 units)
    float mnew = fmaxf(m_run, mx);
    float corr = exp2_hw(m_run - mnew);
    m_run = mnew;
    l_run *= corr;                     // valid on per-lane partials (row-uniform corr)
#pragma unroll
    for (int j = 0; j < 4; ++j) {
      float cj = __shfl(corr, l4 * 4 + j);
#pragma unroll
      for (int nf2 = 0; nf2 < 4; ++nf2) acc_o[nf2][j] *= cj;
    }
  }

  // ---- exp2 + packed bf16 conversion + P write ----
  float ps = 0.f;
#pragma unroll
  for (int nf = 0; nf < 4; ++nf) {
    float p0 = exp2_hw(sc[nf][0] - m_run);
    float p1 = exp2_hw(sc[nf][1] - m_run);
    float p2 = exp2_hw(sc[nf][2] - m_run);
    float p3 = exp2_hw(sc[nf][3] - m_run);
    ps += (p0 + p1) + (p2 + p3);
    unsigned lo, hi;
    asm("v_cvt_pk_bf16_f32 %0, %1, %2" : "=v"(lo) : "v"(p0), "v"(p1));
    asm("v_cvt_pk_bf16_f32 %0, %1, %2" : "=v"(hi) : "v"(p2), "v"(p3));
    uint2 u; u.x = lo; u.y = hi;
    *(uint2*)(pw + nf * 16) = u;   // ds_write_b64
  }
  l_run += ps;   // per-lane partial (16 k-cols of row l15); reduced once at the end

  // ---- P A-fragments (same-wave RAW through LDS) ----
  short8 pf[2];
#pragma unroll
  for (int kc = 0; kc < 2; ++kc)
    pf[kc] = *(const short8*)(pr + kc * 32);

  // ---- PV: V^T B-fragments (swizzled LDS read) ----
  __builtin_amdgcn_s_setprio(1);
#pragma unroll
  for (int nfd = 0; nfd < 4; ++nfd) {
    short8 vf0 = *(const short8*)(vb0 + BUF * 4096 + nfd * 1024);
    short8 vf1 = *(const short8*)(vb1 + BUF * 4096 + nfd * 1024);
    acc_o[nfd] = MFMA16(pf[0], vf0, acc_o[nfd]);
    acc_o[nfd] = MFMA16(pf[1], vf1, acc_o[nfd]);
  }
  __builtin_amdgcn_s_setprio(0);
  __syncthreads();   // drains prefetch (vmcnt) + all waves done with buf[BUF]
}

__global__ __launch_bounds__(512) void attn_fused(
    const unsigned short* __restrict__ Qp, const unsigned short* __restrict__ Kp,
    const unsigned short* __restrict__ Vt, unsigned short* __restrict__ ctx)
{
  __shared__ unsigned short Ks[2][64 * 64];
  __shared__ unsigned short Vts[2][64 * 64];
  __shared__ unsigned short Ps[8][16 * 72];

  // bijective XCD swizzle: 512 blocks, 64 consecutive wg per XCD
  int bid = blockIdx.x;
  int wg = (bid & 7) * 64 + (bid >> 3);
  int h = wg >> 5, qt = wg & 31;

  int t = threadIdx.x, lane = t & 63, w = t >> 6;
  int l15 = lane & 15, l4 = lane >> 4;

  // Q fragments (pre-scaled by 0.125*log2e in projection)
  short8 qf[2];
  int qrow0 = qt * 128 + w * 16;
#pragma unroll
  for (int ks = 0; ks < 2; ++ks)
    qf[ks] = *(const short8*)&Qp[(size_t)(qrow0 + l15) * DM + h * 64 + ks * 32 + l4 * 8];

  float4v acc_o[4] = {};
  float m_run = -INFINITY, l_run = 0.f;

  // ---- precomputed per-lane LDS addresses ----
  const int swz = l15 & 7;
  const unsigned short* kb0 = &Ks[0][l15 * 64 + ((l4) ^ swz) * 8];
  const unsigned short* kb1 = &Ks[0][l15 * 64 + ((4 + l4) ^ swz) * 8];
  const unsigned short* vb0 = &Vts[0][l15 * 64 + ((l4) ^ swz) * 8];
  const unsigned short* vb1 = &Vts[0][l15 * 64 + ((4 + l4) ^ swz) * 8];
  unsigned short* pw = &Ps[w][l15 * 72 + l4 * 4];
  const unsigned short* pr = &Ps[w][l15 * 72 + l4 * 8];

  // ---- staging addresses (512 threads: 1 K-load + 1 V-load each per tile) ----
  int sr = t >> 3, sp = t & 7;
  int slb = sp ^ (sr & 7);
  const unsigned short* kg = Kp + (size_t)sr * DM + h * 64 + slb * 8;
  const unsigned short* vg = Vt + (size_t)(h * 64 + sr) * S_LEN + slb * 8;
  unsigned short* kls = &Ks[0][t * 8];
  unsigned short* vls = &Vts[0][t * 8];

  GLOAD_LDS16(kg, kls);
  GLOAD_LDS16(vg, vls);
  __syncthreads();

  for (int kt = 0; kt < 64; kt += 2) {
    attn_tile<0>(kt,     kb0, kb1, vb0, vb1, pw, pr, kg, vg, kls, vls, qf, acc_o, m_run, l_run, l4);
    attn_tile<1>(kt + 1, kb0, kb1, vb0, vb1, pw, pr, kg, vg, kls, vls, qf, acc_o, m_run, l_run, l4);
  }

  // ---- final l reduction + normalize + write ctx (bf16) ----
  float lr = l_run;
  lr += __shfl_xor(lr, 16);
  lr += __shfl_xor(lr, 32);
#pragma unroll
  for (int j = 0; j < 4; ++j) {
    float lj = __shfl(lr, l4 * 4 + j);   // lane l4*4+j has l15 == l4*4+j (full row sum)
    float inv = 1.0f / lj;
#pragma unroll
    for (int nfd = 0; nfd < 4; ++nfd) {
      int row = qrow0 + l4 * 4 + j;
      int col = h * 64 + nfd * 16 + l15;
      ctx[(size_t)row * DM + col] = f2bf(acc_o[nfd][j] * inv);
    }
  }
}

// ---------------- launcher ----------------
extern "C" void kernel_launch(void* const* d_in, const int* in_sizes, int n_in,
                              void* d_out, int out_size, void* d_ws, size_t ws_size,
                              hipStream_t stream) {
  const float* q  = (const float*)d_in[0];
  const float* k  = (const float*)d_in[1];
  const float* v  = (const float*)d_in[2];
  const float* wq = (const float*)d_in[3];
  const float* bq = (const float*)d_in[4];
  const float* wk = (const float*)d_in[5];
  const float* bk = (const float*)d_in[6];
  const float* wv = (const float*)d_in[7];
  const float* bv = (const float*)d_in[8];
  const float* wo = (const float*)d_in[9];
  const float* bo = (const float*)d_in[10];

  unsigned short* ws  = (unsigned short*)d_ws;
  unsigned short* qb  = ws;                 // 4M elems (reused as ctx later)
  unsigned short* kb  = ws + 4194304u;
  unsigned short* vb  = ws + 8388608u;
  unsigned short* wqb = ws + 12582912u;
  unsigned short* wkb = ws + 13631488u;
  unsigned short* wvb = ws + 14680064u;
  unsigned short* wob = ws + 15728640u;
  unsigned short* Qp  = ws + 16777216u;
  unsigned short* Kp  = ws + 20971520u;
  unsigned short* Vt  = ws + 25165824u;     // V^T [1024][4096]
  unsigned short* ctx = qb;                 // safe reuse: qb consumed by proj_qkv before attn
  float* out = (float*)d_out;

  cast_all<<<dim3(1024, 7), 256, 0, stream>>>(q, k, v, wq, wk, wv, wo, ws);
  proj_qkv<<<dim3(32, 8, 3), 256, 0, stream>>>(qb, kb, vb, wqb, wkb, wvb, Qp, Kp, Vt, bq, bk, bv);
  attn_fused<<<dim3(512), 512, 0, stream>>>(Qp, Kp, Vt, ctx);
  proj_o<<<dim3(32, 8), 256, 0, stream>>>(ctx, wob, out, bo);
}

// Round 16
// 178.563 us; speedup vs baseline: 1.8491x; 1.0285x over previous
//
#include <hip/hip_runtime.h>
#include <stdint.h>

#define S_LEN 4096
#define DM 1024
#define NH 16

typedef __attribute__((ext_vector_type(8))) short short8;
typedef __attribute__((ext_vector_type(4))) float float4v;
typedef __attribute__((ext_vector_type(4))) unsigned short ushort4v;

typedef __attribute__((address_space(1))) const void* as1cvp;
typedef __attribute__((address_space(3))) void* as3vp;

#define MFMA16(a, b, c) __builtin_amdgcn_mfma_f32_16x16x32_bf16((a), (b), (c), 0, 0, 0)
#define GLOAD_LDS16(g, l) \
  __builtin_amdgcn_global_load_lds((as1cvp)(g), (as3vp)(l), 16, 0, 0)

__device__ __forceinline__ unsigned short f2bf(float f) {
  unsigned u = __float_as_uint(f);
  u += 0x7fffu + ((u >> 16) & 1u);
  return (unsigned short)(u >> 16);
}

__device__ __forceinline__ float exp2_hw(float x) {
  float r;
  asm("v_exp_f32 %0, %1" : "=v"(r) : "v"(x));
  return r;
}

// ---------------- cast fp32 -> bf16 into workspace ----------------
__global__ __launch_bounds__(256) void cast_all(
    const float* __restrict__ q, const float* __restrict__ k, const float* __restrict__ v,
    const float* __restrict__ wq, const float* __restrict__ wk, const float* __restrict__ wv,
    const float* __restrict__ wo, unsigned short* __restrict__ dst)
{
  const float* src; size_t off; int n;
  switch (blockIdx.y) {
    case 0: src = q;  off = 0u;        n = 4194304; break;
    case 1: src = k;  off = 4194304u;  n = 4194304; break;
    case 2: src = v;  off = 8388608u;  n = 4194304; break;
    case 3: src = wq; off = 12582912u; n = 1048576; break;
    case 4: src = wk; off = 13631488u; n = 1048576; break;
    case 5: src = wv; off = 14680064u; n = 1048576; break;
    default: src = wo; off = 15728640u; n = 1048576; break;
  }
  int nv = n >> 2;
  for (int i = blockIdx.x * blockDim.x + threadIdx.x; i < nv; i += gridDim.x * blockDim.x) {
    float4v val = ((const float4v*)src)[i];
    ushort4v o;
    o.x = f2bf(val.x); o.y = f2bf(val.y); o.z = f2bf(val.z); o.w = f2bf(val.w);
    ((ushort4v*)(dst + off))[i] = o;
  }
}

// ---------------- 128x128 bt-GEMM tile, BK=64, XOR-swizzled staging ----------------
// Pre-swizzled global source chunk (lb = cb ^ (r&7)), linear LDS dest, same XOR on
// the fragment read (rule #21 both-sides; the attn-proven pattern).
// MODE 0: bf16 row-major out; MODE 1: f32 row-major out;
// MODE 2: bf16 TRANSPOSED out [N][4096] via LDS-transpose coalesced epilogue.
template<int MODE>
__device__ __forceinline__ void gemm128(
    const unsigned short* __restrict__ A, const unsigned short* __restrict__ Bw,
    unsigned short* Cb, float* Cf, const float* __restrict__ bias, float alpha,
    unsigned short* As, unsigned short* Bs, unsigned short* T)
{
  const int K = 1024, N = 1024;
  int bm = blockIdx.x, bn = blockIdx.y;
  int t = threadIdx.x, lane = t & 63, w = t >> 6;
  int l15 = lane & 15, l4 = lane >> 4;
  int wr = w >> 1, wc = w & 1;

  float4v acc[4][4] = {};

  for (int kt = 0; kt < K / 64; ++kt) {
#pragma unroll
    for (int i = 0; i < 4; ++i) {
      int ci = i * 256 + t;            // 0..1023: r = row (0..127), cb = 8-elem chunk (0..7)
      int r = ci >> 3, cb = ci & 7;
      int lb = cb ^ (r & 7);           // pre-swizzled source chunk
      GLOAD_LDS16(A + (size_t)(bm * 128 + r) * K + kt * 64 + lb * 8, As + (size_t)ci * 8);
      GLOAD_LDS16(Bw + (size_t)(bn * 128 + r) * K + kt * 64 + lb * 8, Bs + (size_t)ci * 8);
    }
    __syncthreads();
#pragma unroll
    for (int kk = 0; kk < 2; ++kk) {
      short8 af[4], bfr[4];
#pragma unroll
      for (int mf = 0; mf < 4; ++mf) {
        int row = wr * 64 + mf * 16 + l15;
        int pc = (kk * 4 + l4) ^ (row & 7);
        af[mf] = *(const short8*)&As[row * 64 + pc * 8];
      }
#pragma unroll
      for (int nf = 0; nf < 4; ++nf) {
        int row = wc * 64 + nf * 16 + l15;
        int pc = (kk * 4 + l4) ^ (row & 7);
        bfr[nf] = *(const short8*)&Bs[row * 64 + pc * 8];
      }
#pragma unroll
      for (int mf = 0; mf < 4; ++mf)
#pragma unroll
        for (int nf = 0; nf < 4; ++nf)
          acc[mf][nf] = MFMA16(af[mf], bfr[nf], acc[mf][nf]);
    }
    __syncthreads();
  }

  if (MODE == 2) {
    // ---- LDS-transpose epilogue: T[64][136] bf16, two wc-halves ----
#pragma unroll
    for (int hc = 0; hc < 2; ++hc) {
      if (wc == hc) {
#pragma unroll
        for (int mf = 0; mf < 4; ++mf)
#pragma unroll
          for (int nf = 0; nf < 4; ++nf) {
            int c = nf * 16 + l15;                       // n-local within half
            float bv = bias[bn * 128 + hc * 64 + c];
            ushort4v pk;
#pragma unroll
            for (int j = 0; j < 4; ++j) pk[j] = f2bf((acc[mf][nf][j] + bv) * alpha);
            *(ushort4v*)&T[c * 136 + wr * 64 + mf * 16 + l4 * 4] = pk;  // ds_write_b64
          }
      }
      __syncthreads();
      // coalesced copy: c = t>>2 (0..63), rseg = (t&3)*32
      {
        int c = t >> 2, rseg = (t & 3) * 32;
        size_t gbase = (size_t)(bn * 128 + hc * 64 + c) * S_LEN + bm * 128 + rseg;
#pragma unroll
        for (int s = 0; s < 4; ++s) {
          short8 vv = *(const short8*)&T[c * 136 + rseg + s * 8];
          *(short8*)&Cb[gbase + s * 8] = vv;
        }
      }
      __syncthreads();
    }
    return;
  }

#pragma unroll
  for (int mf = 0; mf < 4; ++mf)
#pragma unroll
    for (int nf = 0; nf < 4; ++nf) {
      int col = bn * 128 + wc * 64 + nf * 16 + l15;
      float bv = bias[col];
#pragma unroll
      for (int j = 0; j < 4; ++j) {
        int row = bm * 128 + wr * 64 + mf * 16 + l4 * 4 + j;
        float val = (acc[mf][nf][j] + bv) * alpha;
        if (MODE == 1) Cf[(size_t)row * N + col] = val;
        else           Cb[(size_t)row * N + col] = f2bf(val);
      }
    }
}

__global__ __launch_bounds__(256) void proj_qkv(
    const unsigned short* xq, const unsigned short* xk, const unsigned short* xv,
    const unsigned short* wq, const unsigned short* wk, const unsigned short* wv,
    unsigned short* Qp, unsigned short* Kp, unsigned short* Vt,
    const float* bq, const float* bk, const float* bv)
{
  __shared__ unsigned short As[128 * 64], Bs[128 * 64];
  __shared__ unsigned short T[64 * 136];   // MODE-2 transpose staging
  switch (blockIdx.z) {
    // Q scale = (1/sqrt(64)) * log2(e): softmax runs in exp2 domain
    case 0:  gemm128<0>(xq, wq, Qp, nullptr, bq, 0.1803368867f, As, Bs, T); break;
    case 1:  gemm128<0>(xk, wk, Kp, nullptr, bk, 1.0f,          As, Bs, T); break;
    default: gemm128<2>(xv, wv, Vt, nullptr, bv, 1.0f,          As, Bs, T); break; // V^T [1024][4096]
  }
}

__global__ __launch_bounds__(256) void proj_o(
    const unsigned short* ctx, const unsigned short* wo, float* out, const float* bo)
{
  __shared__ unsigned short As[128 * 64], Bs[128 * 64];
  gemm128<1>(ctx, wo, nullptr, out, bo, 1.0f, As, Bs, nullptr);
}

// ---------------- fused flash attention (round-15 proven, untouched) ----------------
// 512 blocks (XCD-swizzled) x 512 threads (8 waves), wave = 16 q rows.
// exp2-domain softmax, defer-max THR=11.5, per-lane partial l_run, T5 setprio.
template<int BUF>
__device__ __forceinline__ void attn_tile(
    int kt,
    const unsigned short* kb0, const unsigned short* kb1,
    const unsigned short* vb0, const unsigned short* vb1,
    unsigned short* pw, const unsigned short* pr,
    const unsigned short* kg, const unsigned short* vg,
    unsigned short* kls, unsigned short* vls,
    const short8 (&qf)[2], float4v (&acc_o)[4], float& m_run, float& l_run,
    int l4)
{
  if (kt + 1 < 64) {   // prefetch next tile into the other buffer
    GLOAD_LDS16(kg + (size_t)(kt + 1) * (64 * DM), kls + (1 - BUF) * 4096);
    GLOAD_LDS16(vg + (kt + 1) * 64, vls + (1 - BUF) * 4096);
  }

  // ---- QK^T (swapped: A = K rows, B = Q rows) ----
  float4v sc[4];
  __builtin_amdgcn_s_setprio(1);
#pragma unroll
  for (int nf = 0; nf < 4; ++nf) {
    short8 kf0 = *(const short8*)(kb0 + BUF * 4096 + nf * 1024);
    short8 kf1 = *(const short8*)(kb1 + BUF * 4096 + nf * 1024);
    float4v z = {0.f, 0.f, 0.f, 0.f};
    z = MFMA16(kf0, qf[0], z);
    sc[nf] = MFMA16(kf1, qf[1], z);
  }
  __builtin_amdgcn_s_setprio(0);

  // ---- row max (q = l15), exp2 domain ----
  float mx = fmaxf(fmaxf(fmaxf(sc[0][0], sc[0][1]), sc[0][2]), sc[0][3]);
#pragma unroll
  for (int nf = 1; nf < 4; ++nf)
    mx = fmaxf(fmaxf(fmaxf(fmaxf(mx, sc[nf][0]), sc[nf][1]), sc[nf][2]), sc[nf][3]);
  mx = fmaxf(mx, __shfl_xor(mx, 16));
  mx = fmaxf(mx, __shfl_xor(mx, 32));

  if (!__all(mx <= m_run + 11.5f)) {   // defer-max (11.5 = 8 nats in log2 units)
    float mnew = fmaxf(m_run, mx);
    float corr = exp2_hw(m_run - mnew);
    m_run = mnew;
    l_run *= corr;                     // valid on per-lane partials (row-uniform corr)
#pragma unroll
    for (int j = 0; j < 4; ++j) {
      float cj = __shfl(corr, l4 * 4 + j);
#pragma unroll
      for (int nf2 = 0; nf2 < 4; ++nf2) acc_o[nf2][j] *= cj;
    }
  }

  // ---- exp2 + packed bf16 conversion + P write ----
  float ps = 0.f;
#pragma unroll
  for (int nf = 0; nf < 4; ++nf) {
    float p0 = exp2_hw(sc[nf][0] - m_run);
    float p1 = exp2_hw(sc[nf][1] - m_run);
    float p2 = exp2_hw(sc[nf][2] - m_run);
    float p3 = exp2_hw(sc[nf][3] - m_run);
    ps += (p0 + p1) + (p2 + p3);
    unsigned lo, hi;
    asm("v_cvt_pk_bf16_f32 %0, %1, %2" : "=v"(lo) : "v"(p0), "v"(p1));
    asm("v_cvt_pk_bf16_f32 %0, %1, %2" : "=v"(hi) : "v"(p2), "v"(p3));
    uint2 u; u.x = lo; u.y = hi;
    *(uint2*)(pw + nf * 16) = u;   // ds_write_b64
  }
  l_run += ps;   // per-lane partial (16 k-cols of row l15); reduced once at the end

  // ---- P A-fragments (same-wave RAW through LDS) ----
  short8 pf[2];
#pragma unroll
  for (int kc = 0; kc < 2; ++kc)
    pf[kc] = *(const short8*)(pr + kc * 32);

  // ---- PV: V^T B-fragments (swizzled LDS read) ----
  __builtin_amdgcn_s_setprio(1);
#pragma unroll
  for (int nfd = 0; nfd < 4; ++nfd) {
    short8 vf0 = *(const short8*)(vb0 + BUF * 4096 + nfd * 1024);
    short8 vf1 = *(const short8*)(vb1 + BUF * 4096 + nfd * 1024);
    acc_o[nfd] = MFMA16(pf[0], vf0, acc_o[nfd]);
    acc_o[nfd] = MFMA16(pf[1], vf1, acc_o[nfd]);
  }
  __builtin_amdgcn_s_setprio(0);
  __syncthreads();   // drains prefetch (vmcnt) + all waves done with buf[BUF]
}

__global__ __launch_bounds__(512) void attn_fused(
    const unsigned short* __restrict__ Qp, const unsigned short* __restrict__ Kp,
    const unsigned short* __restrict__ Vt, unsigned short* __restrict__ ctx)
{
  __shared__ unsigned short Ks[2][64 * 64];
  __shared__ unsigned short Vts[2][64 * 64];
  __shared__ unsigned short Ps[8][16 * 72];

  // bijective XCD swizzle: 512 blocks, 64 consecutive wg per XCD
  int bid = blockIdx.x;
  int wg = (bid & 7) * 64 + (bid >> 3);
  int h = wg >> 5, qt = wg & 31;

  int t = threadIdx.x, lane = t & 63, w = t >> 6;
  int l15 = lane & 15, l4 = lane >> 4;

  // Q fragments (pre-scaled by 0.125*log2e in projection)
  short8 qf[2];
  int qrow0 = qt * 128 + w * 16;
#pragma unroll
  for (int ks = 0; ks < 2; ++ks)
    qf[ks] = *(const short8*)&Qp[(size_t)(qrow0 + l15) * DM + h * 64 + ks * 32 + l4 * 8];

  float4v acc_o[4] = {};
  float m_run = -INFINITY, l_run = 0.f;

  // ---- precomputed per-lane LDS addresses ----
  const int swz = l15 & 7;
  const unsigned short* kb0 = &Ks[0][l15 * 64 + ((l4) ^ swz) * 8];
  const unsigned short* kb1 = &Ks[0][l15 * 64 + ((4 + l4) ^ swz) * 8];
  const unsigned short* vb0 = &Vts[0][l15 * 64 + ((l4) ^ swz) * 8];
  const unsigned short* vb1 = &Vts[0][l15 * 64 + ((4 + l4) ^ swz) * 8];
  unsigned short* pw = &Ps[w][l15 * 72 + l4 * 4];
  const unsigned short* pr = &Ps[w][l15 * 72 + l4 * 8];

  // ---- staging addresses (512 threads: 1 K-load + 1 V-load each per tile) ----
  int sr = t >> 3, sp = t & 7;
  int slb = sp ^ (sr & 7);
  const unsigned short* kg = Kp + (size_t)sr * DM + h * 64 + slb * 8;
  const unsigned short* vg = Vt + (size_t)(h * 64 + sr) * S_LEN + slb * 8;
  unsigned short* kls = &Ks[0][t * 8];
  unsigned short* vls = &Vts[0][t * 8];

  GLOAD_LDS16(kg, kls);
  GLOAD_LDS16(vg, vls);
  __syncthreads();

  for (int kt = 0; kt < 64; kt += 2) {
    attn_tile<0>(kt,     kb0, kb1, vb0, vb1, pw, pr, kg, vg, kls, vls, qf, acc_o, m_run, l_run, l4);
    attn_tile<1>(kt + 1, kb0, kb1, vb0, vb1, pw, pr, kg, vg, kls, vls, qf, acc_o, m_run, l_run, l4);
  }

  // ---- final l reduction + normalize + write ctx (bf16) ----
  float lr = l_run;
  lr += __shfl_xor(lr, 16);
  lr += __shfl_xor(lr, 32);
#pragma unroll
  for (int j = 0; j < 4; ++j) {
    float lj = __shfl(lr, l4 * 4 + j);   // lane l4*4+j has l15 == l4*4+j (full row sum)
    float inv = 1.0f / lj;
#pragma unroll
    for (int nfd = 0; nfd < 4; ++nfd) {
      int row = qrow0 + l4 * 4 + j;
      int col = h * 64 + nfd * 16 + l15;
      ctx[(size_t)row * DM + col] = f2bf(acc_o[nfd][j] * inv);
    }
  }
}

// ---------------- launcher ----------------
extern "C" void kernel_launch(void* const* d_in, const int* in_sizes, int n_in,
                              void* d_out, int out_size, void* d_ws, size_t ws_size,
                              hipStream_t stream) {
  const float* q  = (const float*)d_in[0];
  const float* k  = (const float*)d_in[1];
  const float* v  = (const float*)d_in[2];
  const float* wq = (const float*)d_in[3];
  const float* bq = (const float*)d_in[4];
  const float* wk = (const float*)d_in[5];
  const float* bk = (const float*)d_in[6];
  const float* wv = (const float*)d_in[7];
  const float* bv = (const float*)d_in[8];
  const float* wo = (const float*)d_in[9];
  const float* bo = (const float*)d_in[10];

  unsigned short* ws  = (unsigned short*)d_ws;
  unsigned short* qb  = ws;                 // 4M elems (reused as ctx later)
  unsigned short* kb  = ws + 4194304u;
  unsigned short* vb  = ws + 8388608u;
  unsigned short* wqb = ws + 12582912u;
  unsigned short* wkb = ws + 13631488u;
  unsigned short* wvb = ws + 14680064u;
  unsigned short* wob = ws + 15728640u;
  unsigned short* Qp  = ws + 16777216u;
  unsigned short* Kp  = ws + 20971520u;
  unsigned short* Vt  = ws + 25165824u;     // V^T [1024][4096]
  unsigned short* ctx = qb;                 // safe reuse: qb consumed by proj_qkv before attn
  float* out = (float*)d_out;

  cast_all<<<dim3(1024, 7), 256, 0, stream>>>(q, k, v, wq, wk, wv, wo, ws);
  proj_qkv<<<dim3(32, 8, 3), 256, 0, stream>>>(qb, kb, vb, wqb, wkb, wvb, Qp, Kp, Vt, bq, bk, bv);
  attn_fused<<<dim3(512), 512, 0, stream>>>(Qp, Kp, Vt, ctx);
  proj_o<<<dim3(32, 8), 256, 0, stream>>>(ctx, wob, out, bo);
}

// Round 17
// 169.461 us; speedup vs baseline: 1.9484x; 1.0537x over previous
//
#include <hip/hip_runtime.h>
#include <stdint.h>

#define S_LEN 4096
#define DM 1024
#define NH 16

typedef __attribute__((ext_vector_type(8))) short short8;
typedef __attribute__((ext_vector_type(4))) float float4v;
typedef __attribute__((ext_vector_type(4))) unsigned short ushort4v;

typedef __attribute__((address_space(1))) const void* as1cvp;
typedef __attribute__((address_space(3))) void* as3vp;

#define MFMA16(a, b, c) __builtin_amdgcn_mfma_f32_16x16x32_bf16((a), (b), (c), 0, 0, 0)
#define GLOAD_LDS16(g, l) \
  __builtin_amdgcn_global_load_lds((as1cvp)(g), (as3vp)(l), 16, 0, 0)

__device__ __forceinline__ unsigned short f2bf(float f) {
  unsigned u = __float_as_uint(f);
  u += 0x7fffu + ((u >> 16) & 1u);
  return (unsigned short)(u >> 16);
}

__device__ __forceinline__ float exp2_hw(float x) {
  float r;
  asm("v_exp_f32 %0, %1" : "=v"(r) : "v"(x));
  return r;
}

// ---------------- cast fp32 -> bf16 into workspace ----------------
__global__ __launch_bounds__(256) void cast_all(
    const float* __restrict__ q, const float* __restrict__ k, const float* __restrict__ v,
    const float* __restrict__ wq, const float* __restrict__ wk, const float* __restrict__ wv,
    const float* __restrict__ wo, unsigned short* __restrict__ dst)
{
  const float* src; size_t off; int n;
  switch (blockIdx.y) {
    case 0: src = q;  off = 0u;        n = 4194304; break;
    case 1: src = k;  off = 4194304u;  n = 4194304; break;
    case 2: src = v;  off = 8388608u;  n = 4194304; break;
    case 3: src = wq; off = 12582912u; n = 1048576; break;
    case 4: src = wk; off = 13631488u; n = 1048576; break;
    case 5: src = wv; off = 14680064u; n = 1048576; break;
    default: src = wo; off = 15728640u; n = 1048576; break;
  }
  int nv = n >> 2;
  for (int i = blockIdx.x * blockDim.x + threadIdx.x; i < nv; i += gridDim.x * blockDim.x) {
    float4v val = ((const float4v*)src)[i];
    ushort4v o;
    o.x = f2bf(val.x); o.y = f2bf(val.y); o.z = f2bf(val.z); o.w = f2bf(val.w);
    ((ushort4v*)(dst + off))[i] = o;
  }
}

// ---------------- 128x128 bt-GEMM tile, BK=64, XOR-swizzled staging ----------------
// MODE 0: bf16 row-major out;
// MODE 2: bf16 TRANSPOSED out [N][4096] via LDS-transpose coalesced epilogue.
template<int MODE>
__device__ __forceinline__ void gemm128(
    const unsigned short* __restrict__ A, const unsigned short* __restrict__ Bw,
    unsigned short* Cb, const float* __restrict__ bias, float alpha,
    unsigned short* As, unsigned short* Bs, unsigned short* T)
{
  const int K = 1024, N = 1024;
  int bm = blockIdx.x, bn = blockIdx.y;
  int t = threadIdx.x, lane = t & 63, w = t >> 6;
  int l15 = lane & 15, l4 = lane >> 4;
  int wr = w >> 1, wc = w & 1;

  float4v acc[4][4] = {};

  for (int kt = 0; kt < K / 64; ++kt) {
#pragma unroll
    for (int i = 0; i < 4; ++i) {
      int ci = i * 256 + t;            // r = row (0..127), cb = 8-elem chunk (0..7)
      int r = ci >> 3, cb = ci & 7;
      int lb = cb ^ (r & 7);           // pre-swizzled source chunk
      GLOAD_LDS16(A + (size_t)(bm * 128 + r) * K + kt * 64 + lb * 8, As + (size_t)ci * 8);
      GLOAD_LDS16(Bw + (size_t)(bn * 128 + r) * K + kt * 64 + lb * 8, Bs + (size_t)ci * 8);
    }
    __syncthreads();
#pragma unroll
    for (int kk = 0; kk < 2; ++kk) {
      short8 af[4], bfr[4];
#pragma unroll
      for (int mf = 0; mf < 4; ++mf) {
        int row = wr * 64 + mf * 16 + l15;
        int pc = (kk * 4 + l4) ^ (row & 7);
        af[mf] = *(const short8*)&As[row * 64 + pc * 8];
      }
#pragma unroll
      for (int nf = 0; nf < 4; ++nf) {
        int row = wc * 64 + nf * 16 + l15;
        int pc = (kk * 4 + l4) ^ (row & 7);
        bfr[nf] = *(const short8*)&Bs[row * 64 + pc * 8];
      }
#pragma unroll
      for (int mf = 0; mf < 4; ++mf)
#pragma unroll
        for (int nf = 0; nf < 4; ++nf)
          acc[mf][nf] = MFMA16(af[mf], bfr[nf], acc[mf][nf]);
    }
    __syncthreads();
  }

  if (MODE == 2) {
    // ---- LDS-transpose epilogue: T[64][136] bf16, two wc-halves ----
#pragma unroll
    for (int hc = 0; hc < 2; ++hc) {
      if (wc == hc) {
#pragma unroll
        for (int mf = 0; mf < 4; ++mf)
#pragma unroll
          for (int nf = 0; nf < 4; ++nf) {
            int c = nf * 16 + l15;
            float bv = bias[bn * 128 + hc * 64 + c];
            ushort4v pk;
#pragma unroll
            for (int j = 0; j < 4; ++j) pk[j] = f2bf((acc[mf][nf][j] + bv) * alpha);
            *(ushort4v*)&T[c * 136 + wr * 64 + mf * 16 + l4 * 4] = pk;
          }
      }
      __syncthreads();
      {
        int c = t >> 2, rseg = (t & 3) * 32;
        size_t gbase = (size_t)(bn * 128 + hc * 64 + c) * S_LEN + bm * 128 + rseg;
#pragma unroll
        for (int s = 0; s < 4; ++s) {
          short8 vv = *(const short8*)&T[c * 136 + rseg + s * 8];
          *(short8*)&Cb[gbase + s * 8] = vv;
        }
      }
      __syncthreads();
    }
    return;
  }

#pragma unroll
  for (int mf = 0; mf < 4; ++mf)
#pragma unroll
    for (int nf = 0; nf < 4; ++nf) {
      int col = bn * 128 + wc * 64 + nf * 16 + l15;
      float bv = bias[col];
#pragma unroll
      for (int j = 0; j < 4; ++j) {
        int row = bm * 128 + wr * 64 + mf * 16 + l4 * 4 + j;
        Cb[(size_t)row * N + col] = f2bf((acc[mf][nf][j] + bv) * alpha);
      }
    }
}

__global__ __launch_bounds__(256) void proj_qkv(
    const unsigned short* xq, const unsigned short* xk, const unsigned short* xv,
    const unsigned short* wq, const unsigned short* wk, const unsigned short* wv,
    unsigned short* Qp, unsigned short* Kp, unsigned short* Vt,
    const float* bq, const float* bk, const float* bv)
{
  __shared__ unsigned short As[128 * 64], Bs[128 * 64];
  __shared__ unsigned short T[64 * 136];   // MODE-2 transpose staging
  switch (blockIdx.z) {
    // Q scale = (1/sqrt(64)) * log2(e): softmax runs in exp2 domain
    case 0:  gemm128<0>(xq, wq, Qp, bq, 0.1803368867f, As, Bs, T); break;
    case 1:  gemm128<0>(xk, wk, Kp, bk, 1.0f,          As, Bs, T); break;
    default: gemm128<2>(xv, wv, Vt, bv, 1.0f,          As, Bs, T); break; // V^T [1024][4096]
  }
}

// ---------------- proj_o: 128x64 tile, grid (32,16) = 512 blocks = 2/CU ----------------
// Same BK=64 swizzled staging/frag conventions; 4 waves = 4 M-strips of 32 rows.
__global__ __launch_bounds__(256) void proj_o(
    const unsigned short* __restrict__ ctx, const unsigned short* __restrict__ wo,
    float* __restrict__ out, const float* __restrict__ bo)
{
  const int K = 1024, N = 1024;
  __shared__ unsigned short As[128 * 64], Bs[64 * 64];
  int bm = blockIdx.x, bn = blockIdx.y;
  int t = threadIdx.x, lane = t & 63, w = t >> 6;
  int l15 = lane & 15, l4 = lane >> 4;

  float4v acc[2][4] = {};

  for (int kt = 0; kt < K / 64; ++kt) {
#pragma unroll
    for (int i = 0; i < 4; ++i) {     // A: 128 rows x 8 chunks = 1024, 4/thread
      int ci = i * 256 + t;
      int r = ci >> 3, cb = ci & 7;
      int lb = cb ^ (r & 7);
      GLOAD_LDS16(ctx + (size_t)(bm * 128 + r) * K + kt * 64 + lb * 8, As + (size_t)ci * 8);
    }
#pragma unroll
    for (int i = 0; i < 2; ++i) {     // B: 64 rows x 8 chunks = 512, 2/thread
      int ci = i * 256 + t;
      int r = ci >> 3, cb = ci & 7;
      int lb = cb ^ (r & 7);
      GLOAD_LDS16(wo + (size_t)(bn * 64 + r) * K + kt * 64 + lb * 8, Bs + (size_t)ci * 8);
    }
    __syncthreads();
#pragma unroll
    for (int kk = 0; kk < 2; ++kk) {
      short8 af[2], bfr[4];
#pragma unroll
      for (int mf = 0; mf < 2; ++mf) {
        int row = w * 32 + mf * 16 + l15;
        int pc = (kk * 4 + l4) ^ (row & 7);
        af[mf] = *(const short8*)&As[row * 64 + pc * 8];
      }
#pragma unroll
      for (int nf = 0; nf < 4; ++nf) {
        int row = nf * 16 + l15;
        int pc = (kk * 4 + l4) ^ (row & 7);
        bfr[nf] = *(const short8*)&Bs[row * 64 + pc * 8];
      }
#pragma unroll
      for (int mf = 0; mf < 2; ++mf)
#pragma unroll
        for (int nf = 0; nf < 4; ++nf)
          acc[mf][nf] = MFMA16(af[mf], bfr[nf], acc[mf][nf]);
    }
    __syncthreads();
  }

#pragma unroll
  for (int mf = 0; mf < 2; ++mf)
#pragma unroll
    for (int nf = 0; nf < 4; ++nf) {
      int col = bn * 64 + nf * 16 + l15;
      float bv = bo[col];
#pragma unroll
      for (int j = 0; j < 4; ++j) {
        int row = bm * 128 + w * 32 + mf * 16 + l4 * 4 + j;
        out[(size_t)row * N + col] = acc[mf][nf][j] + bv;
      }
    }
}

// ---------------- fused flash attention ----------------
// r15-proven structure; per-tile max shuffles hoisted into the rare defer branch
// (lane-local partial max in the __all is trigger-equivalent; m_run stays
// row-uniform because updates happen only inside the branch with the full reduce).
template<int BUF>
__device__ __forceinline__ void attn_tile(
    int kt,
    const unsigned short* kb0, const unsigned short* kb1,
    const unsigned short* vb0, const unsigned short* vb1,
    unsigned short* pw, const unsigned short* pr,
    const unsigned short* kg, const unsigned short* vg,
    unsigned short* kls, unsigned short* vls,
    const short8 (&qf)[2], float4v (&acc_o)[4], float& m_run, float& l_run,
    int l4)
{
  if (kt + 1 < 64) {   // prefetch next tile into the other buffer
    GLOAD_LDS16(kg + (size_t)(kt + 1) * (64 * DM), kls + (1 - BUF) * 4096);
    GLOAD_LDS16(vg + (kt + 1) * 64, vls + (1 - BUF) * 4096);
  }

  // ---- QK^T (swapped: A = K rows, B = Q rows) ----
  float4v sc[4];
  __builtin_amdgcn_s_setprio(1);
#pragma unroll
  for (int nf = 0; nf < 4; ++nf) {
    short8 kf0 = *(const short8*)(kb0 + BUF * 4096 + nf * 1024);
    short8 kf1 = *(const short8*)(kb1 + BUF * 4096 + nf * 1024);
    float4v z = {0.f, 0.f, 0.f, 0.f};
    z = MFMA16(kf0, qf[0], z);
    sc[nf] = MFMA16(kf1, qf[1], z);
  }
  __builtin_amdgcn_s_setprio(0);

  // ---- lane-local partial row max (exp2 domain); cross-lane reduce only if needed ----
  float mxl = fmaxf(fmaxf(fmaxf(sc[0][0], sc[0][1]), sc[0][2]), sc[0][3]);
#pragma unroll
  for (int nf = 1; nf < 4; ++nf)
    mxl = fmaxf(fmaxf(fmaxf(fmaxf(mxl, sc[nf][0]), sc[nf][1]), sc[nf][2]), sc[nf][3]);

  if (!__all(mxl <= m_run + 11.5f)) {   // defer-max: rarely taken after tile 0
    float mx = fmaxf(mxl, __shfl_xor(mxl, 16));
    mx = fmaxf(mx, __shfl_xor(mx, 32));
    float mnew = fmaxf(m_run, mx);
    float corr = exp2_hw(m_run - mnew);
    m_run = mnew;
    l_run *= corr;                     // valid on per-lane partials (row-uniform corr)
#pragma unroll
    for (int j = 0; j < 4; ++j) {
      float cj = __shfl(corr, l4 * 4 + j);
#pragma unroll
      for (int nf2 = 0; nf2 < 4; ++nf2) acc_o[nf2][j] *= cj;
    }
  }

  // ---- exp2 + packed bf16 conversion + P write ----
  float ps = 0.f;
#pragma unroll
  for (int nf = 0; nf < 4; ++nf) {
    float p0 = exp2_hw(sc[nf][0] - m_run);
    float p1 = exp2_hw(sc[nf][1] - m_run);
    float p2 = exp2_hw(sc[nf][2] - m_run);
    float p3 = exp2_hw(sc[nf][3] - m_run);
    ps += (p0 + p1) + (p2 + p3);
    unsigned lo, hi;
    asm("v_cvt_pk_bf16_f32 %0, %1, %2" : "=v"(lo) : "v"(p0), "v"(p1));
    asm("v_cvt_pk_bf16_f32 %0, %1, %2" : "=v"(hi) : "v"(p2), "v"(p3));
    uint2 u; u.x = lo; u.y = hi;
    *(uint2*)(pw + nf * 16) = u;   // ds_write_b64
  }
  l_run += ps;   // per-lane partial (16 k-cols of row l15); reduced once at the end

  // ---- P A-fragments (same-wave RAW through LDS) ----
  short8 pf[2];
#pragma unroll
  for (int kc = 0; kc < 2; ++kc)
    pf[kc] = *(const short8*)(pr + kc * 32);

  // ---- PV: V^T B-fragments (swizzled LDS read) ----
  __builtin_amdgcn_s_setprio(1);
#pragma unroll
  for (int nfd = 0; nfd < 4; ++nfd) {
    short8 vf0 = *(const short8*)(vb0 + BUF * 4096 + nfd * 1024);
    short8 vf1 = *(const short8*)(vb1 + BUF * 4096 + nfd * 1024);
    acc_o[nfd] = MFMA16(pf[0], vf0, acc_o[nfd]);
    acc_o[nfd] = MFMA16(pf[1], vf1, acc_o[nfd]);
  }
  __builtin_amdgcn_s_setprio(0);
  __syncthreads();   // drains prefetch (vmcnt) + all waves done with buf[BUF]
}

__global__ __launch_bounds__(512) void attn_fused(
    const unsigned short* __restrict__ Qp, const unsigned short* __restrict__ Kp,
    const unsigned short* __restrict__ Vt, unsigned short* __restrict__ ctx)
{
  __shared__ unsigned short Ks[2][64 * 64];
  __shared__ unsigned short Vts[2][64 * 64];
  __shared__ unsigned short Ps[8][16 * 72];

  // bijective XCD swizzle: 512 blocks, 64 consecutive wg per XCD
  int bid = blockIdx.x;
  int wg = (bid & 7) * 64 + (bid >> 3);
  int h = wg >> 5, qt = wg & 31;

  int t = threadIdx.x, lane = t & 63, w = t >> 6;
  int l15 = lane & 15, l4 = lane >> 4;

  // Q fragments (pre-scaled by 0.125*log2e in projection)
  short8 qf[2];
  int qrow0 = qt * 128 + w * 16;
#pragma unroll
  for (int ks = 0; ks < 2; ++ks)
    qf[ks] = *(const short8*)&Qp[(size_t)(qrow0 + l15) * DM + h * 64 + ks * 32 + l4 * 8];

  float4v acc_o[4] = {};
  float m_run = -INFINITY, l_run = 0.f;

  // ---- precomputed per-lane LDS addresses ----
  const int swz = l15 & 7;
  const unsigned short* kb0 = &Ks[0][l15 * 64 + ((l4) ^ swz) * 8];
  const unsigned short* kb1 = &Ks[0][l15 * 64 + ((4 + l4) ^ swz) * 8];
  const unsigned short* vb0 = &Vts[0][l15 * 64 + ((l4) ^ swz) * 8];
  const unsigned short* vb1 = &Vts[0][l15 * 64 + ((4 + l4) ^ swz) * 8];
  unsigned short* pw = &Ps[w][l15 * 72 + l4 * 4];
  const unsigned short* pr = &Ps[w][l15 * 72 + l4 * 8];

  // ---- staging addresses (512 threads: 1 K-load + 1 V-load each per tile) ----
  int sr = t >> 3, sp = t & 7;
  int slb = sp ^ (sr & 7);
  const unsigned short* kg = Kp + (size_t)sr * DM + h * 64 + slb * 8;
  const unsigned short* vg = Vt + (size_t)(h * 64 + sr) * S_LEN + slb * 8;
  unsigned short* kls = &Ks[0][t * 8];
  unsigned short* vls = &Vts[0][t * 8];

  GLOAD_LDS16(kg, kls);
  GLOAD_LDS16(vg, vls);
  __syncthreads();

  for (int kt = 0; kt < 64; kt += 2) {
    attn_tile<0>(kt,     kb0, kb1, vb0, vb1, pw, pr, kg, vg, kls, vls, qf, acc_o, m_run, l_run, l4);
    attn_tile<1>(kt + 1, kb0, kb1, vb0, vb1, pw, pr, kg, vg, kls, vls, qf, acc_o, m_run, l_run, l4);
  }

  // ---- final l reduction + normalize + write ctx (bf16) ----
  float lr = l_run;
  lr += __shfl_xor(lr, 16);
  lr += __shfl_xor(lr, 32);
#pragma unroll
  for (int j = 0; j < 4; ++j) {
    float lj = __shfl(lr, l4 * 4 + j);   // lane l4*4+j has l15 == l4*4+j (full row sum)
    float inv = 1.0f / lj;
#pragma unroll
    for (int nfd = 0; nfd < 4; ++nfd) {
      int row = qrow0 + l4 * 4 + j;
      int col = h * 64 + nfd * 16 + l15;
      ctx[(size_t)row * DM + col] = f2bf(acc_o[nfd][j] * inv);
    }
  }
}

// ---------------- launcher ----------------
extern "C" void kernel_launch(void* const* d_in, const int* in_sizes, int n_in,
                              void* d_out, int out_size, void* d_ws, size_t ws_size,
                              hipStream_t stream) {
  const float* q  = (const float*)d_in[0];
  const float* k  = (const float*)d_in[1];
  const float* v  = (const float*)d_in[2];
  const float* wq = (const float*)d_in[3];
  const float* bq = (const float*)d_in[4];
  const float* wk = (const float*)d_in[5];
  const float* bk = (const float*)d_in[6];
  const float* wv = (const float*)d_in[7];
  const float* bv = (const float*)d_in[8];
  const float* wo = (const float*)d_in[9];
  const float* bo = (const float*)d_in[10];

  unsigned short* ws  = (unsigned short*)d_ws;
  unsigned short* qb  = ws;                 // 4M elems (reused as ctx later)
  unsigned short* kb  = ws + 4194304u;
  unsigned short* vb  = ws + 8388608u;
  unsigned short* wqb = ws + 12582912u;
  unsigned short* wkb = ws + 13631488u;
  unsigned short* wvb = ws + 14680064u;
  unsigned short* wob = ws + 15728640u;
  unsigned short* Qp  = ws + 16777216u;
  unsigned short* Kp  = ws + 20971520u;
  unsigned short* Vt  = ws + 25165824u;     // V^T [1024][4096]
  unsigned short* ctx = qb;                 // safe reuse: qb consumed by proj_qkv before attn
  float* out = (float*)d_out;

  cast_all<<<dim3(1024, 7), 256, 0, stream>>>(q, k, v, wq, wk, wv, wo, ws);
  proj_qkv<<<dim3(32, 8, 3), 256, 0, stream>>>(qb, kb, vb, wqb, wkb, wvb, Qp, Kp, Vt, bq, bk, bv);
  attn_fused<<<dim3(512), 512, 0, stream>>>(Qp, Kp, Vt, ctx);
  proj_o<<<dim3(32, 16), 256, 0, stream>>>(ctx, wob, out, bo);
}

// Round 19
// 167.654 us; speedup vs baseline: 1.9694x; 1.0108x over previous
//
#include <hip/hip_runtime.h>
#include <stdint.h>

#define S_LEN 4096
#define DM 1024
#define NH 16

typedef __attribute__((ext_vector_type(8))) short short8;
typedef __attribute__((ext_vector_type(4))) float float4v;
typedef __attribute__((ext_vector_type(4))) unsigned short ushort4v;

typedef __attribute__((address_space(1))) const void* as1cvp;
typedef __attribute__((address_space(3))) void* as3vp;

#define MFMA16(a, b, c) __builtin_amdgcn_mfma_f32_16x16x32_bf16((a), (b), (c), 0, 0, 0)
#define GLOAD_LDS16(g, l) \
  __builtin_amdgcn_global_load_lds((as1cvp)(g), (as3vp)(l), 16, 0, 0)

__device__ __forceinline__ unsigned short f2bf(float f) {
  unsigned u = __float_as_uint(f);
  u += 0x7fffu + ((u >> 16) & 1u);
  return (unsigned short)(u >> 16);
}

__device__ __forceinline__ float exp2_hw(float x) {
  float r;
  asm("v_exp_f32 %0, %1" : "=v"(r) : "v"(x));
  return r;
}

// ---------------- cast fp32 -> bf16 into workspace ----------------
__global__ __launch_bounds__(256) void cast_all(
    const float* __restrict__ q, const float* __restrict__ k, const float* __restrict__ v,
    const float* __restrict__ wq, const float* __restrict__ wk, const float* __restrict__ wv,
    const float* __restrict__ wo, unsigned short* __restrict__ dst)
{
  const float* src; size_t off; int n;
  switch (blockIdx.y) {
    case 0: src = q;  off = 0u;        n = 4194304; break;
    case 1: src = k;  off = 4194304u;  n = 4194304; break;
    case 2: src = v;  off = 8388608u;  n = 4194304; break;
    case 3: src = wq; off = 12582912u; n = 1048576; break;
    case 4: src = wk; off = 13631488u; n = 1048576; break;
    case 5: src = wv; off = 14680064u; n = 1048576; break;
    default: src = wo; off = 15728640u; n = 1048576; break;
  }
  int nv = n >> 2;
  for (int i = blockIdx.x * blockDim.x + threadIdx.x; i < nv; i += gridDim.x * blockDim.x) {
    float4v val = ((const float4v*)src)[i];
    ushort4v o;
    o.x = f2bf(val.x); o.y = f2bf(val.y); o.z = f2bf(val.z); o.w = f2bf(val.w);
    ((ushort4v*)(dst + off))[i] = o;
  }
}

// ---------------- 128x128 bt-GEMM tile, BK=64, XOR-swizzled staging ----------------
// MODE 0: bf16 row-major out;
// MODE 2: bf16 TRANSPOSED out [N][4096] via LDS-transpose coalesced epilogue.
template<int MODE>
__device__ __forceinline__ void gemm128(
    const unsigned short* __restrict__ A, const unsigned short* __restrict__ Bw,
    unsigned short* Cb, const float* __restrict__ bias, float alpha,
    unsigned short* As, unsigned short* Bs, unsigned short* T)
{
  const int K = 1024, N = 1024;
  int bm = blockIdx.x, bn = blockIdx.y;
  int t = threadIdx.x, lane = t & 63, w = t >> 6;
  int l15 = lane & 15, l4 = lane >> 4;
  int wr = w >> 1, wc = w & 1;

  float4v acc[4][4] = {};

  for (int kt = 0; kt < K / 64; ++kt) {
#pragma unroll
    for (int i = 0; i < 4; ++i) {
      int ci = i * 256 + t;            // r = row (0..127), cb = 8-elem chunk (0..7)
      int r = ci >> 3, cb = ci & 7;
      int lb = cb ^ (r & 7);           // pre-swizzled source chunk
      GLOAD_LDS16(A + (size_t)(bm * 128 + r) * K + kt * 64 + lb * 8, As + (size_t)ci * 8);
      GLOAD_LDS16(Bw + (size_t)(bn * 128 + r) * K + kt * 64 + lb * 8, Bs + (size_t)ci * 8);
    }
    __syncthreads();
#pragma unroll
    for (int kk = 0; kk < 2; ++kk) {
      short8 af[4], bfr[4];
#pragma unroll
      for (int mf = 0; mf < 4; ++mf) {
        int row = wr * 64 + mf * 16 + l15;
        int pc = (kk * 4 + l4) ^ (row & 7);
        af[mf] = *(const short8*)&As[row * 64 + pc * 8];
      }
#pragma unroll
      for (int nf = 0; nf < 4; ++nf) {
        int row = wc * 64 + nf * 16 + l15;
        int pc = (kk * 4 + l4) ^ (row & 7);
        bfr[nf] = *(const short8*)&Bs[row * 64 + pc * 8];
      }
#pragma unroll
      for (int mf = 0; mf < 4; ++mf)
#pragma unroll
        for (int nf = 0; nf < 4; ++nf)
          acc[mf][nf] = MFMA16(af[mf], bfr[nf], acc[mf][nf]);
    }
    __syncthreads();
  }

  if (MODE == 2) {
    // ---- LDS-transpose epilogue: T[64][136] bf16, two wc-halves ----
#pragma unroll
    for (int hc = 0; hc < 2; ++hc) {
      if (wc == hc) {
#pragma unroll
        for (int mf = 0; mf < 4; ++mf)
#pragma unroll
          for (int nf = 0; nf < 4; ++nf) {
            int c = nf * 16 + l15;
            float bv = bias[bn * 128 + hc * 64 + c];
            ushort4v pk;
#pragma unroll
            for (int j = 0; j < 4; ++j) pk[j] = f2bf((acc[mf][nf][j] + bv) * alpha);
            *(ushort4v*)&T[c * 136 + wr * 64 + mf * 16 + l4 * 4] = pk;
          }
      }
      __syncthreads();
      {
        int c = t >> 2, rseg = (t & 3) * 32;
        size_t gbase = (size_t)(bn * 128 + hc * 64 + c) * S_LEN + bm * 128 + rseg;
#pragma unroll
        for (int s = 0; s < 4; ++s) {
          short8 vv = *(const short8*)&T[c * 136 + rseg + s * 8];
          *(short8*)&Cb[gbase + s * 8] = vv;
        }
      }
      __syncthreads();
    }
    return;
  }

#pragma unroll
  for (int mf = 0; mf < 4; ++mf)
#pragma unroll
    for (int nf = 0; nf < 4; ++nf) {
      int col = bn * 128 + wc * 64 + nf * 16 + l15;
      float bv = bias[col];
#pragma unroll
      for (int j = 0; j < 4; ++j) {
        int row = bm * 128 + wr * 64 + mf * 16 + l4 * 4 + j;
        Cb[(size_t)row * N + col] = f2bf((acc[mf][nf][j] + bv) * alpha);
      }
    }
}

__global__ __launch_bounds__(256) void proj_qkv(
    const unsigned short* xq, const unsigned short* xk, const unsigned short* xv,
    const unsigned short* wq, const unsigned short* wk, const unsigned short* wv,
    unsigned short* Qp, unsigned short* Kp, unsigned short* Vt,
    const float* bq, const float* bk, const float* bv)
{
  __shared__ unsigned short As[128 * 64], Bs[128 * 64];
  __shared__ unsigned short T[64 * 136];   // MODE-2 transpose staging
  switch (blockIdx.z) {
    // Q scale = (1/sqrt(64)) * log2(e): softmax runs in exp2 domain
    case 0:  gemm128<0>(xq, wq, Qp, bq, 0.1803368867f, As, Bs, T); break;
    case 1:  gemm128<0>(xk, wk, Kp, bk, 1.0f,          As, Bs, T); break;
    default: gemm128<2>(xv, wv, Vt, bv, 1.0f,          As, Bs, T); break; // V^T [1024][4096]
  }
}

// ---------------- proj_o: 128x64 tile, grid (32,16) = 512 blocks = 2/CU ----------------
__global__ __launch_bounds__(256) void proj_o(
    const unsigned short* __restrict__ ctx, const unsigned short* __restrict__ wo,
    float* __restrict__ out, const float* __restrict__ bo)
{
  const int K = 1024, N = 1024;
  __shared__ unsigned short As[128 * 64], Bs[64 * 64];
  int bm = blockIdx.x, bn = blockIdx.y;
  int t = threadIdx.x, lane = t & 63, w = t >> 6;
  int l15 = lane & 15, l4 = lane >> 4;

  float4v acc[2][4] = {};

  for (int kt = 0; kt < K / 64; ++kt) {
#pragma unroll
    for (int i = 0; i < 4; ++i) {     // A: 128 rows x 8 chunks
      int ci = i * 256 + t;
      int r = ci >> 3, cb = ci & 7;
      int lb = cb ^ (r & 7);
      GLOAD_LDS16(ctx + (size_t)(bm * 128 + r) * K + kt * 64 + lb * 8, As + (size_t)ci * 8);
    }
#pragma unroll
    for (int i = 0; i < 2; ++i) {     // B: 64 rows x 8 chunks
      int ci = i * 256 + t;
      int r = ci >> 3, cb = ci & 7;
      int lb = cb ^ (r & 7);
      GLOAD_LDS16(wo + (size_t)(bn * 64 + r) * K + kt * 64 + lb * 8, Bs + (size_t)ci * 8);
    }
    __syncthreads();
#pragma unroll
    for (int kk = 0; kk < 2; ++kk) {
      short8 af[2], bfr[4];
#pragma unroll
      for (int mf = 0; mf < 2; ++mf) {
        int row = w * 32 + mf * 16 + l15;
        int pc = (kk * 4 + l4) ^ (row & 7);
        af[mf] = *(const short8*)&As[row * 64 + pc * 8];
      }
#pragma unroll
      for (int nf = 0; nf < 4; ++nf) {
        int row = nf * 16 + l15;
        int pc = (kk * 4 + l4) ^ (row & 7);
        bfr[nf] = *(const short8*)&Bs[row * 64 + pc * 8];
      }
#pragma unroll
      for (int mf = 0; mf < 2; ++mf)
#pragma unroll
        for (int nf = 0; nf < 4; ++nf)
          acc[mf][nf] = MFMA16(af[mf], bfr[nf], acc[mf][nf]);
    }
    __syncthreads();
  }

#pragma unroll
  for (int mf = 0; mf < 2; ++mf)
#pragma unroll
    for (int nf = 0; nf < 4; ++nf) {
      int col = bn * 64 + nf * 16 + l15;
      float bv = bo[col];
#pragma unroll
      for (int j = 0; j < 4; ++j) {
        int row = bm * 128 + w * 32 + mf * 16 + l4 * 4 + j;
        out[(size_t)row * N + col] = acc[mf][nf][j] + bv;
      }
    }
}

// ---------------- fused flash attention ----------------
// r17 math; RING-4 buffering (2 tiles per barrier -> 32 barrier events).
// P: stride 64 elems (exact payload) + XOR block-swizzle (same involution both
// sides, rule #21): logical 8-elem block b of row l15 stored at b^(l15&7).
// LDS = 32K(K) + 32K(V) + 16K(P) = 81920 B exactly -> 2 blocks/CU (160KB pool).
template<int BUF>
__device__ __forceinline__ void attn_tile(
    const unsigned short* kb0, const unsigned short* kb1,
    const unsigned short* vb0, const unsigned short* vb1,
    unsigned short* pwrow, const int (&pwo)[4],
    const unsigned short* pr0, const unsigned short* pr1,
    const short8 (&qf)[2], float4v (&acc_o)[4], float& m_run, float& l_run,
    int l4)
{
  // ---- QK^T (swapped: A = K rows, B = Q rows) ----
  float4v sc[4];
  __builtin_amdgcn_s_setprio(1);
#pragma unroll
  for (int nf = 0; nf < 4; ++nf) {
    short8 kf0 = *(const short8*)(kb0 + BUF * 4096 + nf * 1024);
    short8 kf1 = *(const short8*)(kb1 + BUF * 4096 + nf * 1024);
    float4v z = {0.f, 0.f, 0.f, 0.f};
    z = MFMA16(kf0, qf[0], z);
    sc[nf] = MFMA16(kf1, qf[1], z);
  }
  __builtin_amdgcn_s_setprio(0);

  // ---- lane-local partial row max; cross-lane reduce only in rare branch ----
  float mxl = fmaxf(fmaxf(fmaxf(sc[0][0], sc[0][1]), sc[0][2]), sc[0][3]);
#pragma unroll
  for (int nf = 1; nf < 4; ++nf)
    mxl = fmaxf(fmaxf(fmaxf(fmaxf(mxl, sc[nf][0]), sc[nf][1]), sc[nf][2]), sc[nf][3]);

  if (!__all(mxl <= m_run + 11.5f)) {   // defer-max: rarely taken after tile 0
    float mx = fmaxf(mxl, __shfl_xor(mxl, 16));
    mx = fmaxf(mx, __shfl_xor(mx, 32));
    float mnew = fmaxf(m_run, mx);
    float corr = exp2_hw(m_run - mnew);
    m_run = mnew;
    l_run *= corr;                     // valid on per-lane partials (row-uniform corr)
#pragma unroll
    for (int j = 0; j < 4; ++j) {
      float cj = __shfl(corr, l4 * 4 + j);
#pragma unroll
      for (int nf2 = 0; nf2 < 4; ++nf2) acc_o[nf2][j] *= cj;
    }
  }

  // ---- exp2 + packed bf16 conversion + P write (swizzled block offsets) ----
  float ps = 0.f;
#pragma unroll
  for (int nf = 0; nf < 4; ++nf) {
    float p0 = exp2_hw(sc[nf][0] - m_run);
    float p1 = exp2_hw(sc[nf][1] - m_run);
    float p2 = exp2_hw(sc[nf][2] - m_run);
    float p3 = exp2_hw(sc[nf][3] - m_run);
    ps += (p0 + p1) + (p2 + p3);
    unsigned lo, hi;
    asm("v_cvt_pk_bf16_f32 %0, %1, %2" : "=v"(lo) : "v"(p0), "v"(p1));
    asm("v_cvt_pk_bf16_f32 %0, %1, %2" : "=v"(hi) : "v"(p2), "v"(p3));
    uint2 u; u.x = lo; u.y = hi;
    *(uint2*)(pwrow + pwo[nf]) = u;   // ds_write_b64
  }
  l_run += ps;   // per-lane partial (16 k-cols of row l15); reduced once at the end

  // ---- P A-fragments (same-wave RAW through LDS, swizzled read) ----
  short8 pf[2];
  pf[0] = *(const short8*)pr0;
  pf[1] = *(const short8*)pr1;

  // ---- PV: V^T B-fragments (swizzled LDS read) ----
  __builtin_amdgcn_s_setprio(1);
#pragma unroll
  for (int nfd = 0; nfd < 4; ++nfd) {
    short8 vf0 = *(const short8*)(vb0 + BUF * 4096 + nfd * 1024);
    short8 vf1 = *(const short8*)(vb1 + BUF * 4096 + nfd * 1024);
    acc_o[nfd] = MFMA16(pf[0], vf0, acc_o[nfd]);
    acc_o[nfd] = MFMA16(pf[1], vf1, acc_o[nfd]);
  }
  __builtin_amdgcn_s_setprio(0);
}

__global__ __launch_bounds__(512) void attn_fused(
    const unsigned short* __restrict__ Qp, const unsigned short* __restrict__ Kp,
    const unsigned short* __restrict__ Vt, unsigned short* __restrict__ ctx)
{
  __shared__ unsigned short Ks[4][64 * 64];
  __shared__ unsigned short Vts[4][64 * 64];
  __shared__ unsigned short Ps[8][16 * 64];   // 81920 B total -> 2 blocks/CU

  // bijective XCD swizzle: 512 blocks, 64 consecutive wg per XCD
  int bid = blockIdx.x;
  int wg = (bid & 7) * 64 + (bid >> 3);
  int h = wg >> 5, qt = wg & 31;

  int t = threadIdx.x, lane = t & 63, w = t >> 6;
  int l15 = lane & 15, l4 = lane >> 4;

  // Q fragments (pre-scaled by 0.125*log2e in projection)
  short8 qf[2];
  int qrow0 = qt * 128 + w * 16;
#pragma unroll
  for (int ks = 0; ks < 2; ++ks)
    qf[ks] = *(const short8*)&Qp[(size_t)(qrow0 + l15) * DM + h * 64 + ks * 32 + l4 * 8];

  float4v acc_o[4] = {};
  float m_run = -INFINITY, l_run = 0.f;

  // ---- precomputed per-lane LDS addresses (buffer 0 base; +BUF*4096 imm) ----
  const int swz = l15 & 7;
  const unsigned short* kb0 = &Ks[0][l15 * 64 + ((l4) ^ swz) * 8];
  const unsigned short* kb1 = &Ks[0][l15 * 64 + ((4 + l4) ^ swz) * 8];
  const unsigned short* vb0 = &Vts[0][l15 * 64 + ((l4) ^ swz) * 8];
  const unsigned short* vb1 = &Vts[0][l15 * 64 + ((4 + l4) ^ swz) * 8];
  // P row base + swizzled write offsets (block = 2nf + (l4>>1)) and read ptrs
  unsigned short* pwrow = &Ps[w][l15 * 64];
  int pwo[4];
#pragma unroll
  for (int nf = 0; nf < 4; ++nf)
    pwo[nf] = ((2 * nf + (l4 >> 1)) ^ swz) * 8 + (l4 & 1) * 4;
  const unsigned short* pr0 = &Ps[w][l15 * 64 + ((l4) ^ swz) * 8];
  const unsigned short* pr1 = &Ps[w][l15 * 64 + ((4 + l4) ^ swz) * 8];

  // ---- staging addresses (512 threads: 1 K-load + 1 V-load each per tile) ----
  int sr = t >> 3, sp = t & 7;
  int slb = sp ^ (sr & 7);
  const unsigned short* kg = Kp + (size_t)sr * DM + h * 64 + slb * 8;
  const unsigned short* vg = Vt + (size_t)(h * 64 + sr) * S_LEN + slb * 8;
  unsigned short* kls = &Ks[0][t * 8];
  unsigned short* vls = &Vts[0][t * 8];

#define STAGE_T(BUFI, ktv) do {                                      \
    GLOAD_LDS16(kg + (size_t)(ktv) * (64 * DM), kls + (BUFI) * 4096); \
    GLOAD_LDS16(vg + (ktv) * 64,                vls + (BUFI) * 4096); \
  } while (0)

  STAGE_T(0, 0);
  STAGE_T(1, 1);
  __syncthreads();

  for (int kt = 0; kt < 64; kt += 4) {
    if (kt + 2 < 64) STAGE_T(2, kt + 2);
    if (kt + 3 < 64) STAGE_T(3, kt + 3);
    attn_tile<0>(kb0, kb1, vb0, vb1, pwrow, pwo, pr0, pr1, qf, acc_o, m_run, l_run, l4);
    attn_tile<1>(kb0, kb1, vb0, vb1, pwrow, pwo, pr0, pr1, qf, acc_o, m_run, l_run, l4);
    __syncthreads();                 // drains stage(kt+2,kt+3); waves done with buf0/1
    if (kt + 4 < 64) STAGE_T(0, kt + 4);
    if (kt + 5 < 64) STAGE_T(1, kt + 5);
    attn_tile<2>(kb0, kb1, vb0, vb1, pwrow, pwo, pr0, pr1, qf, acc_o, m_run, l_run, l4);
    attn_tile<3>(kb0, kb1, vb0, vb1, pwrow, pwo, pr0, pr1, qf, acc_o, m_run, l_run, l4);
    __syncthreads();                 // drains stage(kt+4,kt+5); waves done with buf2/3
  }
#undef STAGE_T

  // ---- final l reduction + normalize + write ctx (bf16) ----
  float lr = l_run;
  lr += __shfl_xor(lr, 16);
  lr += __shfl_xor(lr, 32);
#pragma unroll
  for (int j = 0; j < 4; ++j) {
    float lj = __shfl(lr, l4 * 4 + j);   // lane l4*4+j has l15 == l4*4+j (full row sum)
    float inv = 1.0f / lj;
#pragma unroll
    for (int nfd = 0; nfd < 4; ++nfd) {
      int row = qrow0 + l4 * 4 + j;
      int col = h * 64 + nfd * 16 + l15;
      ctx[(size_t)row * DM + col] = f2bf(acc_o[nfd][j] * inv);
    }
  }
}

// ---------------- launcher ----------------
extern "C" void kernel_launch(void* const* d_in, const int* in_sizes, int n_in,
                              void* d_out, int out_size, void* d_ws, size_t ws_size,
                              hipStream_t stream) {
  const float* q  = (const float*)d_in[0];
  const float* k  = (const float*)d_in[1];
  const float* v  = (const float*)d_in[2];
  const float* wq = (const float*)d_in[3];
  const float* bq = (const float*)d_in[4];
  const float* wk = (const float*)d_in[5];
  const float* bk = (const float*)d_in[6];
  const float* wv = (const float*)d_in[7];
  const float* bv = (const float*)d_in[8];
  const float* wo = (const float*)d_in[9];
  const float* bo = (const float*)d_in[10];

  unsigned short* ws  = (unsigned short*)d_ws;
  unsigned short* qb  = ws;                 // 4M elems (reused as ctx later)
  unsigned short* kb  = ws + 4194304u;
  unsigned short* vb  = ws + 8388608u;
  unsigned short* wqb = ws + 12582912u;
  unsigned short* wkb = ws + 13631488u;
  unsigned short* wvb = ws + 14680064u;
  unsigned short* wob = ws + 15728640u;
  unsigned short* Qp  = ws + 16777216u;
  unsigned short* Kp  = ws + 20971520u;
  unsigned short* Vt  = ws + 25165824u;     // V^T [1024][4096]
  unsigned short* ctx = qb;                 // safe reuse: qb consumed by proj_qkv before attn
  float* out = (float*)d_out;

  cast_all<<<dim3(1024, 7), 256, 0, stream>>>(q, k, v, wq, wk, wv, wo, ws);
  proj_qkv<<<dim3(32, 8, 3), 256, 0, stream>>>(qb, kb, vb, wqb, wkb, wvb, Qp, Kp, Vt, bq, bk, bv);
  attn_fused<<<dim3(512), 512, 0, stream>>>(Qp, Kp, Vt, ctx);
  proj_o<<<dim3(32, 16), 256, 0, stream>>>(ctx, wob, out, bo);
}